// Round 11
// baseline (384.425 us; speedup 1.0000x reference)
//
#include <hip/hip_runtime.h>
#include <hip/hip_bf16.h>

#define N_NODES 100000
#define N_EDGES 1000000
#define N_GRAPHS 2048
#define F_IN 128
#define NEG_SLOPE 0.2f
#define E_TOT (N_EDGES + N_NODES)       // edges + self-loops
#define GEMM_BLOCKS 782                 // ceil(100000/128)
#define NODE_BLOCKS 391                 // ceil(100000/256)
#define NB 1563                         // coarse buckets = ceil(N_NODES/64)
#define EB 1075                         // edge blocks = ceil(E_TOT/1024)
#define CP_BLOCKS 7                     // ceil(NB/256)

typedef short  bf16x8 __attribute__((ext_vector_type(8)));
typedef float  f32x16 __attribute__((ext_vector_type(16)));

__device__ __forceinline__ short f2bf(float f) {      // RNE f32 -> bf16 bits
    unsigned u = __float_as_uint(f);
    unsigned r = (u + 0x7fffu + ((u >> 16) & 1u)) >> 16;
    return (short)r;
}
__device__ __forceinline__ float bf2f(short h) {
    return __uint_as_float(((unsigned)(unsigned short)h) << 16);
}

// ---- DPP helpers (ctrl is a template constant) ------------------------------
template <int CTRL>
__device__ __forceinline__ float dpp_add(float x) {
    return x + __int_as_float(__builtin_amdgcn_update_dpp(
        0, __float_as_int(x), CTRL, 0xf, 0xf, true));
}
__device__ __forceinline__ float head_sum_bcast(float x) {
    x = dpp_add<0x111>(x);   // row_shr:1
    x = dpp_add<0x112>(x);   // row_shr:2
    x = dpp_add<0x114>(x);   // row_shr:4
    x = dpp_add<0x118>(x);   // row_shr:8
    x = dpp_add<0x142>(x);   // row_bcast:15
    return __int_as_float(__builtin_amdgcn_ds_swizzle(__float_as_int(x), 0x03E0));
}
__device__ __forceinline__ float full_sum64(float x) {
    x = dpp_add<0x111>(x);
    x = dpp_add<0x112>(x);
    x = dpp_add<0x114>(x);
    x = dpp_add<0x118>(x);
    x = dpp_add<0x142>(x);   // row_bcast:15
    x = dpp_add<0x143>(x);   // row_bcast:31
    return x;
}
__device__ __forceinline__ float quad_sum(float x) {
    x = dpp_add<0xB1>(x);    // quad_perm [1,0,3,2]
    x = dpp_add<0x4E>(x);    // quad_perm [2,3,0,1]
    return x;
}

// ========== K1: xlr = x @ [W_l|W_r] (split-bf16 MFMA) ========================
__global__ __launch_bounds__(256) void k_gemm(const float* __restrict__ x,
                                              const float* __restrict__ Wl,
                                              const float* __restrict__ Wr,
                                              float* __restrict__ xlr) {
    __shared__ short wt[2][128][136];           // [hi/lo][n][k], +8 bf16 pad
    int tid = threadIdx.x;
    {   // ---- stage W transposed + split (once) ----
        int k  = tid >> 1;                      // 0..127
        int cq = tid & 1;                       // 0: cols 0-63 (Wl), 1: 64-127 (Wr)
        const float* Wsrc = cq ? Wr : Wl;
#pragma unroll
        for (int u = 0; u < 16; ++u) {
            int c0 = u * 4;
            float4 wv = *(const float4*)(Wsrc + (size_t)k * 64 + c0);
            float vv[4] = {wv.x, wv.y, wv.z, wv.w};
#pragma unroll
            for (int q = 0; q < 4; ++q) {
                int c = cq * 64 + c0 + q;
                short hi = f2bf(vv[q]);
                wt[0][c][k] = hi;
                wt[1][c][k] = f2bf(vv[q] - bf2f(hi));
            }
        }
    }
    __syncthreads();
    int lane = tid & 63, w = tid >> 6;
    int m = lane & 31, half = lane >> 5;
    int row = blockIdx.x * 128 + w * 32 + m;
    bool rv = row < N_NODES;
    const float* xrow = x + (size_t)(rv ? row : 0) * F_IN;
    f32x16 acc[4];
#pragma unroll
    for (int t = 0; t < 4; ++t)
#pragma unroll
        for (int i = 0; i < 16; ++i) acc[t][i] = 0.f;

#pragma unroll
    for (int kt = 0; kt < 8; ++kt) {            // K=16 steps
        int kb = kt * 16 + half * 8;
        float4 xa = rv ? *(const float4*)(xrow + kb)
                       : make_float4(0.f, 0.f, 0.f, 0.f);
        float4 xb = rv ? *(const float4*)(xrow + kb + 4)
                       : make_float4(0.f, 0.f, 0.f, 0.f);
        float xs[8] = {xa.x, xa.y, xa.z, xa.w, xb.x, xb.y, xb.z, xb.w};
        bf16x8 ahi, alo;
#pragma unroll
        for (int j = 0; j < 8; ++j) {
            short hi = f2bf(xs[j]);
            ahi[j] = hi;
            alo[j] = f2bf(xs[j] - bf2f(hi));
        }
#pragma unroll
        for (int t = 0; t < 4; ++t) {
            int n = t * 32 + m;
            bf16x8 bhi = *(const bf16x8*)&wt[0][n][kb];
            bf16x8 blo = *(const bf16x8*)&wt[1][n][kb];
            acc[t] = __builtin_amdgcn_mfma_f32_32x32x16_bf16(ahi, bhi, acc[t], 0, 0, 0);
            acc[t] = __builtin_amdgcn_mfma_f32_32x32x16_bf16(ahi, blo, acc[t], 0, 0, 0);
            acc[t] = __builtin_amdgcn_mfma_f32_32x32x16_bf16(alo, bhi, acc[t], 0, 0, 0);
        }
    }
    int r0 = blockIdx.x * 128 + w * 32 + 4 * half;
#pragma unroll
    for (int t = 0; t < 4; ++t)
#pragma unroll
        for (int reg = 0; reg < 16; ++reg) {
            int rr = r0 + (reg & 3) + 8 * (reg >> 2);
            if (rr < N_NODES)
                xlr[(size_t)rr * 128 + t * 32 + m] = acc[t][reg];
        }
}

// ========== K2: per-block coarse-bucket histogram (LDS atomics only) ==========
__global__ __launch_bounds__(256) void k_bhist(const int* __restrict__ ei,
                                               int* __restrict__ bhist) {
    __shared__ int lh[NB];
    int tid = threadIdx.x, b = blockIdx.x;
    for (int i = tid; i < NB; i += 256) lh[i] = 0;
    __syncthreads();
    int e0 = b * 1024;
#pragma unroll
    for (int j = 0; j < 4; ++j) {
        int e = e0 + j * 256 + tid;
        if (e < E_TOT) {
            int d = (e < N_EDGES) ? ei[N_EDGES + e] : (e - N_EDGES);
            atomicAdd(&lh[d >> 6], 1);
        }
    }
    __syncthreads();
    for (int i = tid; i < NB; i += 256) bhist[(size_t)b * NB + i] = lh[i];
}

// ========== K3: column running-prefix over blocks (in-place) + bounds =========
__global__ __launch_bounds__(256) void k_colprefix_bounds(int* __restrict__ bhist,
                                                          int* __restrict__ colsum,
                                                          const int* __restrict__ batch,
                                                          int* __restrict__ start) {
    if (blockIdx.x < CP_BLOCKS) {
        int i = blockIdx.x * 256 + threadIdx.x;
        if (i >= NB) return;
        int run = 0;
#pragma unroll 4
        for (int b = 0; b < EB; ++b) {
            int t = bhist[(size_t)b * NB + i];
            bhist[(size_t)b * NB + i] = run;
            run += t;
        }
        colsum[i] = run;
    } else {
        int i = (blockIdx.x - CP_BLOCKS) * 256 + threadIdx.x;
        if (i >= N_NODES) return;
        int bi = batch[i];
        int bp = (i == 0) ? -1 : batch[i - 1];
        for (int g = bp + 1; g <= bi; ++g) start[g] = i;
        if (i == N_NODES - 1)
            for (int g = bi + 1; g <= N_GRAPHS; ++g) start[g] = N_NODES;
    }
}

// ========== K4: exclusive scan of colsum -> colbase (bucket bases) ============
__global__ __launch_bounds__(256) void k_cbscan(const int* __restrict__ colsum,
                                                int* __restrict__ colbase) {
    __shared__ int sh[256];
    int t = threadIdx.x;
    int v[7]; int s = 0;
#pragma unroll
    for (int k = 0; k < 7; ++k) {
        int idx = t * 7 + k;
        v[k] = (idx < NB) ? colsum[idx] : 0;
        s += v[k];
    }
    sh[t] = s; __syncthreads();
    for (int off = 1; off < 256; off <<= 1) {
        int xv = (t >= off) ? sh[t - off] : 0;
        __syncthreads();
        sh[t] += xv;
        __syncthreads();
    }
    int run = sh[t] - s;
#pragma unroll
    for (int k = 0; k < 7; ++k) {
        int idx = t * 7 + k;
        if (idx <= NB) colbase[idx] = run;
        run += v[k];
    }
}

// ========== K5: scatter edges into coarse buckets (LDS ranks, plain stores) ===
__global__ __launch_bounds__(256) void k_bscatter(const int* __restrict__ ei,
                                                  const int* __restrict__ bhist,
                                                  const int* __restrict__ colbase,
                                                  int* __restrict__ bpack) {
    __shared__ int lh[NB];
    int tid = threadIdx.x, b = blockIdx.x;
    for (int i = tid; i < NB; i += 256) lh[i] = 0;
    __syncthreads();
    int e0 = b * 1024;
#pragma unroll
    for (int j = 0; j < 4; ++j) {
        int e = e0 + j * 256 + tid;
        if (e < E_TOT) {
            int s, d;
            if (e < N_EDGES) { s = ei[e]; d = ei[N_EDGES + e]; }
            else             { s = d = e - N_EDGES; }
            int bk = d >> 6;
            int lr = atomicAdd(&lh[bk], 1);
            int pos = colbase[bk] + bhist[(size_t)b * NB + bk] + lr;
            bpack[pos] = s | ((d & 63) << 17);  // src in 17 bits, local dst in 6
        }
    }
}

// ========== K6: per-bucket fine grouping -> rowptr + sorted_src ===============
__global__ __launch_bounds__(256) void k_fine(const int* __restrict__ bpack,
                                              const int* __restrict__ colbase,
                                              int* __restrict__ rowptr,
                                              int* __restrict__ sorted_src) {
    __shared__ int fcnt[64];
    __shared__ int foff[64];
    int i = blockIdx.x, tid = threadIdx.x;
    int cb0 = colbase[i], cb1 = colbase[i + 1];
    if (tid < 64) fcnt[tid] = 0;
    __syncthreads();
    for (int e = cb0 + tid; e < cb1; e += 256)
        atomicAdd(&fcnt[bpack[e] >> 17], 1);
    __syncthreads();
    if (tid < 64) {                             // wave 0: scan of 64 counts
        int v = fcnt[tid];
        int inc = v;
#pragma unroll
        for (int o = 1; o < 64; o <<= 1) {
            int t = __shfl_up(inc, o, 64);
            if (tid >= o) inc += t;
        }
        int excl = inc - v;
        foff[tid] = excl;
        int node = i * 64 + tid;
        if (node <= N_NODES) rowptr[node] = cb0 + excl;
    }
    __syncthreads();
    for (int e = cb0 + tid; e < cb1; e += 256) {
        int w = bpack[e];
        int lr = atomicAdd(&foff[w >> 17], 1);
        sorted_src[cb0 + lr] = w & 131071;
    }
}

// ========== K7: fused GATv2 per dst — no-max softmax, scalarized CSR + DPP ====
__global__ __launch_bounds__(256) void k_gat(const float* __restrict__ xlr,
                                             const int* __restrict__ rowptr,
                                             const int* __restrict__ sorted_src,
                                             const float* __restrict__ att,
                                             const float* __restrict__ bias,
                                             const float* __restrict__ w_rel,
                                             const float* __restrict__ w_root,
                                             float* __restrict__ hfeat,
                                             float* __restrict__ tbuf,
                                             float* __restrict__ rbuf) {
    int lane = threadIdx.x & 63;
    int du = __builtin_amdgcn_readfirstlane(blockIdx.x * 4 + (threadIdx.x >> 6));
    if (du >= N_NODES) return;
    float xr_l  = xlr[(size_t)du * 128 + 64 + lane];
    float att_l = att[lane];
    int j0 = __builtin_amdgcn_readfirstlane(rowptr[du]);
    int j1 = __builtin_amdgcn_readfirstlane(rowptr[du + 1]);
    float wsum = 0.f, acc = 0.f;
    int jc = j0;
    for (; jc + 8 <= j1; jc += 8) {             // full chunks of 8
        int sv = sorted_src[jc + (lane & 7)];
        float p[8], xv[8];
#pragma unroll
        for (int i = 0; i < 8; ++i) {
            int s = __builtin_amdgcn_readlane(sv, i);
            xv[i] = (xlr + (size_t)(unsigned)s * 128)[lane];
        }
#pragma unroll
        for (int i = 0; i < 8; ++i) {
            float v = xv[i] + xr_l;
            v = (v > 0.f) ? v : NEG_SLOPE * v;
            p[i] = v * att_l;
        }
#pragma unroll
        for (int i = 0; i < 8; ++i)
            p[i] = head_sum_bcast(p[i]);
#pragma unroll
        for (int i = 0; i < 8; ++i) {
            float w = __expf(p[i]);             // logits bounded; no max needed
            wsum += w;
            acc += w * xv[i];
        }
    }
    for (; jc < j1; jc += 4) {                  // masked chunks of 4
        int n = j1 - jc;
        int jj = jc + (lane & 3);
        if (jj > j1 - 1) jj = j1 - 1;
        int sv = sorted_src[jj];
        float p[4], xv[4];
#pragma unroll
        for (int i = 0; i < 4; ++i) {
            int s = __builtin_amdgcn_readlane(sv, i);
            xv[i] = (xlr + (size_t)(unsigned)s * 128)[lane];
        }
#pragma unroll
        for (int i = 0; i < 4; ++i) {
            float v = xv[i] + xr_l;
            v = (v > 0.f) ? v : NEG_SLOPE * v;
            p[i] = v * att_l;
        }
#pragma unroll
        for (int i = 0; i < 4; ++i)
            p[i] = head_sum_bcast(p[i]);
#pragma unroll
        for (int i = 0; i < 4; ++i) {
            float w = (i < n) ? __expf(p[i]) : 0.f;
            wsum += w;
            acc += w * xv[i];
        }
    }
    float h = acc / wsum + bias[lane];
    hfeat[(size_t)du * 64 + lane] = h;
    float a = full_sum64(h * w_rel[lane]);
    float b = full_sum64(h * w_root[lane]);
    if (lane == 63) { tbuf[du] = a; rbuf[du] = b; }
}

// ========== K8: fused score + per-graph softmax-pool (block per graph) ========
__global__ __launch_bounds__(256) void k_pool(const int* __restrict__ rowptr,
                                              const int* __restrict__ sorted_src,
                                              const float* __restrict__ t,
                                              const float* __restrict__ r,
                                              const float* __restrict__ b_score,
                                              float* __restrict__ score,
                                              const float* __restrict__ h,
                                              const int* __restrict__ start,
                                              float* __restrict__ out) {
    __shared__ float sh[4];
    __shared__ float shacc[4][64];
    int g = blockIdx.x;
    int tid = threadIdx.x, w = tid >> 6, lane = tid & 63;
    int n0 = start[g], n1 = start[g + 1];
    int cnt = n1 - n0;
    if (cnt <= 0) { if (tid < 64) out[(size_t)g * 64 + tid] = 0.f; return; }
    float bsc = b_score[0];
    for (int base = n0; base < n1; base += 64) {
        int i = base + (tid >> 2);
        float sum = 0.f;
        int jj0 = 0, jj1 = 0;
        if (i < n1) { jj0 = rowptr[i]; jj1 = rowptr[i + 1]; }
        for (int j = jj0 + (tid & 3); j < jj1; j += 4)
            sum += t[sorted_src[j]];
        sum = quad_sum(sum);
        if (i < n1 && (tid & 3) == 0)
            score[i] = sum - t[i] + r[i] + bsc;
    }
    __syncthreads();
    float m = -1e30f;
    for (int i = n0 + tid; i < n1; i += 256) m = fmaxf(m, score[i]);
#pragma unroll
    for (int o = 32; o; o >>= 1) m = fmaxf(m, __shfl_xor(m, o, 64));
    if (lane == 0) sh[w] = m;
    __syncthreads();
    m = fmaxf(fmaxf(sh[0], sh[1]), fmaxf(sh[2], sh[3]));
    float ssum = 0.f;
    for (int i = n0 + tid; i < n1; i += 256) ssum += __expf(score[i] - m);
#pragma unroll
    for (int o = 32; o; o >>= 1) ssum += __shfl_xor(ssum, o, 64);
    __syncthreads();
    if (lane == 0) sh[w] = ssum;
    __syncthreads();
    ssum = sh[0] + sh[1] + sh[2] + sh[3];
    float acc = 0.f;
    for (int i = n0 + w; i < n1; i += 4)
        acc += __expf(score[i] - m) * h[(size_t)i * 64 + lane];
    shacc[w][lane] = acc;
    __syncthreads();
    if (w == 0) {
        float tot = shacc[0][lane] + shacc[1][lane] + shacc[2][lane] + shacc[3][lane];
        out[(size_t)g * 64 + lane] = tot * (1.f + 1.f / (float)cnt) / ssum;
    }
}

extern "C" void kernel_launch(void* const* d_in, const int* in_sizes, int n_in,
                              void* d_out, int out_size, void* d_ws, size_t ws_size,
                              hipStream_t stream) {
    const float* x      = (const float*)d_in[0];
    const int*   ei     = (const int*)d_in[1];
    const int*   batch  = (const int*)d_in[2];
    const float* Wl     = (const float*)d_in[3];
    const float* Wr     = (const float*)d_in[4];
    const float* att    = (const float*)d_in[5];
    const float* bias   = (const float*)d_in[6];
    const float* w_rel  = (const float*)d_in[7];
    const float* w_root = (const float*)d_in[8];
    const float* b_sc   = (const float*)d_in[9];

    char* ws = (char*)d_ws;
    size_t off = 0;
    auto alloc = [&](size_t bytes) { void* p = ws + off; off += (bytes + 255) & ~255ull; return p; };
    float* xlr        = (float*)alloc((size_t)N_NODES * 128 * 4);       // 51.2 MB
    float* hfeat      = (float*)alloc((size_t)N_NODES * 64 * 4);        // 25.6 MB
    int*   bhist      = (int*)hfeat;   // alias: bhist (6.7 MB) dead before k_gat writes hfeat
    int*   bpack      = (int*)  alloc((size_t)E_TOT * 4);               // 4.4 MB
    int*   sorted_src = (int*)  alloc((size_t)E_TOT * 4);               // 4.4 MB
    int*   rowptr     = (int*)  alloc((size_t)(N_NODES + 1) * 4);
    int*   colsum     = (int*)  alloc((size_t)NB * 4);
    int*   colbase    = (int*)  alloc((size_t)(NB + 1) * 4);
    float* tbuf       = (float*)alloc((size_t)N_NODES * 4);
    float* rbuf       = (float*)alloc((size_t)N_NODES * 4);
    float* score      = (float*)alloc((size_t)N_NODES * 4);
    int*   start      = (int*)  alloc((size_t)(N_GRAPHS + 1) * 4);

    k_gemm            <<<GEMM_BLOCKS, 256, 0, stream>>>(x, Wl, Wr, xlr);
    k_bhist           <<<EB, 256, 0, stream>>>(ei, bhist);
    k_colprefix_bounds<<<CP_BLOCKS + NODE_BLOCKS, 256, 0, stream>>>(bhist, colsum, batch, start);
    k_cbscan          <<<1, 256, 0, stream>>>(colsum, colbase);
    k_bscatter        <<<EB, 256, 0, stream>>>(ei, bhist, colbase, bpack);
    k_fine            <<<NB, 256, 0, stream>>>(bpack, colbase, rowptr, sorted_src);
    k_gat             <<<(N_NODES + 3) / 4, 256, 0, stream>>>(xlr, rowptr, sorted_src, att, bias,
                                                              w_rel, w_root, hfeat, tbuf, rbuf);
    k_pool            <<<N_GRAPHS, 256, 0, stream>>>(rowptr, sorted_src, tbuf, rbuf, b_sc,
                                                     score, hfeat, start, (float*)d_out);
}

// Round 12
// 243.913 us; speedup vs baseline: 1.5761x; 1.5761x over previous
//
#include <hip/hip_runtime.h>
#include <hip/hip_bf16.h>

#define N_NODES 100000
#define N_EDGES 1000000
#define N_GRAPHS 2048
#define F_IN 128
#define NEG_SLOPE 0.2f
#define E_TOT (N_EDGES + N_NODES)       // edges + self-loops
#define GEMM_BLOCKS 782                 // ceil(100000/128)
#define NODE_BLOCKS 391                 // ceil(100000/256)
#define NB 1563                         // coarse buckets = ceil(N_NODES/64)
#define EB 269                          // edge blocks = ceil(E_TOT/4096)
#define EB_PAD 272
#define CPW_BLOCKS 391                  // ceil(NB/4) wave-per-bucket scan blocks

typedef short  bf16x8 __attribute__((ext_vector_type(8)));
typedef float  f32x16 __attribute__((ext_vector_type(16)));

__device__ __forceinline__ short f2bf(float f) {      // RNE f32 -> bf16 bits
    unsigned u = __float_as_uint(f);
    unsigned r = (u + 0x7fffu + ((u >> 16) & 1u)) >> 16;
    return (short)r;
}
__device__ __forceinline__ float bf2f(short h) {
    return __uint_as_float(((unsigned)(unsigned short)h) << 16);
}

// ---- DPP helpers (ctrl is a template constant) ------------------------------
template <int CTRL>
__device__ __forceinline__ float dpp_add(float x) {
    return x + __int_as_float(__builtin_amdgcn_update_dpp(
        0, __float_as_int(x), CTRL, 0xf, 0xf, true));
}
__device__ __forceinline__ float head_sum_bcast(float x) {
    x = dpp_add<0x111>(x);   // row_shr:1
    x = dpp_add<0x112>(x);   // row_shr:2
    x = dpp_add<0x114>(x);   // row_shr:4
    x = dpp_add<0x118>(x);   // row_shr:8
    x = dpp_add<0x142>(x);   // row_bcast:15
    return __int_as_float(__builtin_amdgcn_ds_swizzle(__float_as_int(x), 0x03E0));
}
__device__ __forceinline__ float full_sum64(float x) {
    x = dpp_add<0x111>(x);
    x = dpp_add<0x112>(x);
    x = dpp_add<0x114>(x);
    x = dpp_add<0x118>(x);
    x = dpp_add<0x142>(x);   // row_bcast:15
    x = dpp_add<0x143>(x);   // row_bcast:31
    return x;
}
__device__ __forceinline__ float quad_sum(float x) {
    x = dpp_add<0xB1>(x);    // quad_perm [1,0,3,2]
    x = dpp_add<0x4E>(x);    // quad_perm [2,3,0,1]
    return x;
}

// ========== K1: xlr = x @ [W_l|W_r] (split-bf16 MFMA) ========================
__global__ __launch_bounds__(256) void k_gemm(const float* __restrict__ x,
                                              const float* __restrict__ Wl,
                                              const float* __restrict__ Wr,
                                              float* __restrict__ xlr) {
    __shared__ short wt[2][128][136];           // [hi/lo][n][k], +8 bf16 pad
    int tid = threadIdx.x;
    {   // ---- stage W transposed + split (once) ----
        int k  = tid >> 1;                      // 0..127
        int cq = tid & 1;                       // 0: cols 0-63 (Wl), 1: 64-127 (Wr)
        const float* Wsrc = cq ? Wr : Wl;
#pragma unroll
        for (int u = 0; u < 16; ++u) {
            int c0 = u * 4;
            float4 wv = *(const float4*)(Wsrc + (size_t)k * 64 + c0);
            float vv[4] = {wv.x, wv.y, wv.z, wv.w};
#pragma unroll
            for (int q = 0; q < 4; ++q) {
                int c = cq * 64 + c0 + q;
                short hi = f2bf(vv[q]);
                wt[0][c][k] = hi;
                wt[1][c][k] = f2bf(vv[q] - bf2f(hi));
            }
        }
    }
    __syncthreads();
    int lane = tid & 63, w = tid >> 6;
    int m = lane & 31, half = lane >> 5;
    int row = blockIdx.x * 128 + w * 32 + m;
    bool rv = row < N_NODES;
    const float* xrow = x + (size_t)(rv ? row : 0) * F_IN;
    f32x16 acc[4];
#pragma unroll
    for (int t = 0; t < 4; ++t)
#pragma unroll
        for (int i = 0; i < 16; ++i) acc[t][i] = 0.f;

#pragma unroll
    for (int kt = 0; kt < 8; ++kt) {            // K=16 steps
        int kb = kt * 16 + half * 8;
        float4 xa = rv ? *(const float4*)(xrow + kb)
                       : make_float4(0.f, 0.f, 0.f, 0.f);
        float4 xb = rv ? *(const float4*)(xrow + kb + 4)
                       : make_float4(0.f, 0.f, 0.f, 0.f);
        float xs[8] = {xa.x, xa.y, xa.z, xa.w, xb.x, xb.y, xb.z, xb.w};
        bf16x8 ahi, alo;
#pragma unroll
        for (int j = 0; j < 8; ++j) {
            short hi = f2bf(xs[j]);
            ahi[j] = hi;
            alo[j] = f2bf(xs[j] - bf2f(hi));
        }
#pragma unroll
        for (int t = 0; t < 4; ++t) {
            int n = t * 32 + m;
            bf16x8 bhi = *(const bf16x8*)&wt[0][n][kb];
            bf16x8 blo = *(const bf16x8*)&wt[1][n][kb];
            acc[t] = __builtin_amdgcn_mfma_f32_32x32x16_bf16(ahi, bhi, acc[t], 0, 0, 0);
            acc[t] = __builtin_amdgcn_mfma_f32_32x32x16_bf16(ahi, blo, acc[t], 0, 0, 0);
            acc[t] = __builtin_amdgcn_mfma_f32_32x32x16_bf16(alo, bhi, acc[t], 0, 0, 0);
        }
    }
    int r0 = blockIdx.x * 128 + w * 32 + 4 * half;
#pragma unroll
    for (int t = 0; t < 4; ++t)
#pragma unroll
        for (int reg = 0; reg < 16; ++reg) {
            int rr = r0 + (reg & 3) + 8 * (reg >> 2);
            if (rr < N_NODES)
                xlr[(size_t)rr * 128 + t * 32 + m] = acc[t][reg];
        }
}

// ========== K2: coarse histogram, bucket-major output [NB][EB_PAD] ============
__global__ __launch_bounds__(256) void k_bhist(const int* __restrict__ ei,
                                               int* __restrict__ bhist) {
    __shared__ int lh[NB];
    int tid = threadIdx.x, b = blockIdx.x;
    for (int i = tid; i < NB; i += 256) lh[i] = 0;
    __syncthreads();
    int e0 = b * 4096;
#pragma unroll
    for (int j = 0; j < 16; ++j) {
        int e = e0 + j * 256 + tid;
        if (e < E_TOT) {
            int d = (e < N_EDGES) ? ei[N_EDGES + e] : (e - N_EDGES);
            atomicAdd(&lh[d >> 6], 1);
        }
    }
    __syncthreads();
    for (int i = tid; i < NB; i += 256)
        bhist[(size_t)i * EB_PAD + b] = lh[i];  // bucket-major
}

// ========== K3: wave-per-bucket exclusive scan over blocks + bounds ===========
__global__ __launch_bounds__(256) void k_colprefix_bounds(int* __restrict__ bhist,
                                                          int* __restrict__ colsum,
                                                          const int* __restrict__ batch,
                                                          int* __restrict__ start) {
    if (blockIdx.x < CPW_BLOCKS) {
        int wv = blockIdx.x * 4 + (threadIdx.x >> 6);   // bucket id, wave-uniform
        if (wv >= NB) return;
        int lane = threadIdx.x & 63;
        int* row = bhist + (size_t)wv * EB_PAD;
        int carry = 0;
        for (int base = 0; base < EB; base += 64) {
            int idx = base + lane;
            int v = (idx < EB) ? row[idx] : 0;
            int inc = v;
#pragma unroll
            for (int o = 1; o < 64; o <<= 1) {
                int t = __shfl_up(inc, o, 64);
                if (lane >= o) inc += t;
            }
            int tot = __shfl(inc, 63, 64);
            if (idx < EB) row[idx] = carry + inc - v;   // exclusive prefix
            carry += tot;
        }
        if (lane == 0) colsum[wv] = carry;
    } else {
        int i = (blockIdx.x - CPW_BLOCKS) * 256 + threadIdx.x;
        if (i >= N_NODES) return;
        int bi = batch[i];
        int bp = (i == 0) ? -1 : batch[i - 1];
        for (int g = bp + 1; g <= bi; ++g) start[g] = i;
        if (i == N_NODES - 1)
            for (int g = bi + 1; g <= N_GRAPHS; ++g) start[g] = N_NODES;
    }
}

// ========== K4: exclusive scan of colsum -> colbase (bucket bases) ============
__global__ __launch_bounds__(256) void k_cbscan(const int* __restrict__ colsum,
                                                int* __restrict__ colbase) {
    __shared__ int sh[256];
    int t = threadIdx.x;
    int v[7]; int s = 0;
#pragma unroll
    for (int k = 0; k < 7; ++k) {
        int idx = t * 7 + k;
        v[k] = (idx < NB) ? colsum[idx] : 0;
        s += v[k];
    }
    sh[t] = s; __syncthreads();
    for (int off = 1; off < 256; off <<= 1) {
        int xv = (t >= off) ? sh[t - off] : 0;
        __syncthreads();
        sh[t] += xv;
        __syncthreads();
    }
    int run = sh[t] - s;
#pragma unroll
    for (int k = 0; k < 7; ++k) {
        int idx = t * 7 + k;
        if (idx <= NB) colbase[idx] = run;
        run += v[k];
    }
}

// ========== K5: scatter edges into coarse buckets (LDS ranks, plain stores) ===
__global__ __launch_bounds__(256) void k_bscatter(const int* __restrict__ ei,
                                                  const int* __restrict__ bhist,
                                                  const int* __restrict__ colbase,
                                                  int* __restrict__ bpack) {
    __shared__ int lh[NB];
    int tid = threadIdx.x, b = blockIdx.x;
    for (int i = tid; i < NB; i += 256) lh[i] = 0;
    __syncthreads();
    int e0 = b * 4096;
#pragma unroll
    for (int j = 0; j < 16; ++j) {
        int e = e0 + j * 256 + tid;
        if (e < E_TOT) {
            int s, d;
            if (e < N_EDGES) { s = ei[e]; d = ei[N_EDGES + e]; }
            else             { s = d = e - N_EDGES; }
            int bk = d >> 6;
            int lr = atomicAdd(&lh[bk], 1);
            int pos = colbase[bk] + bhist[(size_t)bk * EB_PAD + b] + lr;
            bpack[pos] = s | ((d & 63) << 17);  // src in 17 bits, local dst in 6
        }
    }
}

// ========== K6: per-bucket fine grouping -> rowptr + sorted_src ===============
__global__ __launch_bounds__(256) void k_fine(const int* __restrict__ bpack,
                                              const int* __restrict__ colbase,
                                              int* __restrict__ rowptr,
                                              int* __restrict__ sorted_src) {
    __shared__ int fcnt[64];
    __shared__ int foff[64];
    int i = blockIdx.x, tid = threadIdx.x;
    int cb0 = colbase[i], cb1 = colbase[i + 1];
    if (tid < 64) fcnt[tid] = 0;
    __syncthreads();
    for (int e = cb0 + tid; e < cb1; e += 256)
        atomicAdd(&fcnt[bpack[e] >> 17], 1);
    __syncthreads();
    if (tid < 64) {                             // wave 0: scan of 64 counts
        int v = fcnt[tid];
        int inc = v;
#pragma unroll
        for (int o = 1; o < 64; o <<= 1) {
            int t = __shfl_up(inc, o, 64);
            if (tid >= o) inc += t;
        }
        int excl = inc - v;
        foff[tid] = excl;
        int node = i * 64 + tid;
        if (node <= N_NODES) rowptr[node] = cb0 + excl;
    }
    __syncthreads();
    for (int e = cb0 + tid; e < cb1; e += 256) {
        int w = bpack[e];
        int lr = atomicAdd(&foff[w >> 17], 1);
        sorted_src[cb0 + lr] = w & 131071;
    }
}

// ========== K7: fused GATv2 per dst — no-max softmax, scalarized CSR + DPP ====
__global__ __launch_bounds__(256) void k_gat(const float* __restrict__ xlr,
                                             const int* __restrict__ rowptr,
                                             const int* __restrict__ sorted_src,
                                             const float* __restrict__ att,
                                             const float* __restrict__ bias,
                                             const float* __restrict__ w_rel,
                                             const float* __restrict__ w_root,
                                             float* __restrict__ hfeat,
                                             float* __restrict__ tbuf,
                                             float* __restrict__ rbuf) {
    int lane = threadIdx.x & 63;
    int du = __builtin_amdgcn_readfirstlane(blockIdx.x * 4 + (threadIdx.x >> 6));
    if (du >= N_NODES) return;
    float xr_l  = xlr[(size_t)du * 128 + 64 + lane];
    float att_l = att[lane];
    int j0 = __builtin_amdgcn_readfirstlane(rowptr[du]);
    int j1 = __builtin_amdgcn_readfirstlane(rowptr[du + 1]);
    float wsum = 0.f, acc = 0.f;
    int jc = j0;
    for (; jc + 8 <= j1; jc += 8) {             // full chunks of 8
        int sv = sorted_src[jc + (lane & 7)];
        float p[8], xv[8];
#pragma unroll
        for (int i = 0; i < 8; ++i) {
            int s = __builtin_amdgcn_readlane(sv, i);
            xv[i] = (xlr + (size_t)(unsigned)s * 128)[lane];
        }
#pragma unroll
        for (int i = 0; i < 8; ++i) {
            float v = xv[i] + xr_l;
            v = (v > 0.f) ? v : NEG_SLOPE * v;
            p[i] = v * att_l;
        }
#pragma unroll
        for (int i = 0; i < 8; ++i)
            p[i] = head_sum_bcast(p[i]);
#pragma unroll
        for (int i = 0; i < 8; ++i) {
            float w = __expf(p[i]);             // logits bounded; no max needed
            wsum += w;
            acc += w * xv[i];
        }
    }
    for (; jc < j1; jc += 4) {                  // masked chunks of 4
        int n = j1 - jc;
        int jj = jc + (lane & 3);
        if (jj > j1 - 1) jj = j1 - 1;
        int sv = sorted_src[jj];
        float p[4], xv[4];
#pragma unroll
        for (int i = 0; i < 4; ++i) {
            int s = __builtin_amdgcn_readlane(sv, i);
            xv[i] = (xlr + (size_t)(unsigned)s * 128)[lane];
        }
#pragma unroll
        for (int i = 0; i < 4; ++i) {
            float v = xv[i] + xr_l;
            v = (v > 0.f) ? v : NEG_SLOPE * v;
            p[i] = v * att_l;
        }
#pragma unroll
        for (int i = 0; i < 4; ++i)
            p[i] = head_sum_bcast(p[i]);
#pragma unroll
        for (int i = 0; i < 4; ++i) {
            float w = (i < n) ? __expf(p[i]) : 0.f;
            wsum += w;
            acc += w * xv[i];
        }
    }
    float h = acc / wsum + bias[lane];
    hfeat[(size_t)du * 64 + lane] = h;
    float a = full_sum64(h * w_rel[lane]);
    float b = full_sum64(h * w_root[lane]);
    if (lane == 63) { tbuf[du] = a; rbuf[du] = b; }
}

// ========== K8: fused score + per-graph softmax-pool (block per graph) ========
__global__ __launch_bounds__(256) void k_pool(const int* __restrict__ rowptr,
                                              const int* __restrict__ sorted_src,
                                              const float* __restrict__ t,
                                              const float* __restrict__ r,
                                              const float* __restrict__ b_score,
                                              float* __restrict__ score,
                                              const float* __restrict__ h,
                                              const int* __restrict__ start,
                                              float* __restrict__ out) {
    __shared__ float sh[4];
    __shared__ float shacc[4][64];
    int g = blockIdx.x;
    int tid = threadIdx.x, w = tid >> 6, lane = tid & 63;
    int n0 = start[g], n1 = start[g + 1];
    int cnt = n1 - n0;
    if (cnt <= 0) { if (tid < 64) out[(size_t)g * 64 + tid] = 0.f; return; }
    float bsc = b_score[0];
    for (int base = n0; base < n1; base += 64) {
        int i = base + (tid >> 2);
        float sum = 0.f;
        int jj0 = 0, jj1 = 0;
        if (i < n1) { jj0 = rowptr[i]; jj1 = rowptr[i + 1]; }
        for (int j = jj0 + (tid & 3); j < jj1; j += 4)
            sum += t[sorted_src[j]];
        sum = quad_sum(sum);
        if (i < n1 && (tid & 3) == 0)
            score[i] = sum - t[i] + r[i] + bsc;
    }
    __syncthreads();
    float m = -1e30f;
    for (int i = n0 + tid; i < n1; i += 256) m = fmaxf(m, score[i]);
#pragma unroll
    for (int o = 32; o; o >>= 1) m = fmaxf(m, __shfl_xor(m, o, 64));
    if (lane == 0) sh[w] = m;
    __syncthreads();
    m = fmaxf(fmaxf(sh[0], sh[1]), fmaxf(sh[2], sh[3]));
    float ssum = 0.f;
    for (int i = n0 + tid; i < n1; i += 256) ssum += __expf(score[i] - m);
#pragma unroll
    for (int o = 32; o; o >>= 1) ssum += __shfl_xor(ssum, o, 64);
    __syncthreads();
    if (lane == 0) sh[w] = ssum;
    __syncthreads();
    ssum = sh[0] + sh[1] + sh[2] + sh[3];
    float acc = 0.f;
    for (int i = n0 + w; i < n1; i += 4)
        acc += __expf(score[i] - m) * h[(size_t)i * 64 + lane];
    shacc[w][lane] = acc;
    __syncthreads();
    if (w == 0) {
        float tot = shacc[0][lane] + shacc[1][lane] + shacc[2][lane] + shacc[3][lane];
        out[(size_t)g * 64 + lane] = tot * (1.f + 1.f / (float)cnt) / ssum;
    }
}

extern "C" void kernel_launch(void* const* d_in, const int* in_sizes, int n_in,
                              void* d_out, int out_size, void* d_ws, size_t ws_size,
                              hipStream_t stream) {
    const float* x      = (const float*)d_in[0];
    const int*   ei     = (const int*)d_in[1];
    const int*   batch  = (const int*)d_in[2];
    const float* Wl     = (const float*)d_in[3];
    const float* Wr     = (const float*)d_in[4];
    const float* att    = (const float*)d_in[5];
    const float* bias   = (const float*)d_in[6];
    const float* w_rel  = (const float*)d_in[7];
    const float* w_root = (const float*)d_in[8];
    const float* b_sc   = (const float*)d_in[9];

    char* ws = (char*)d_ws;
    size_t off = 0;
    auto alloc = [&](size_t bytes) { void* p = ws + off; off += (bytes + 255) & ~255ull; return p; };
    float* xlr        = (float*)alloc((size_t)N_NODES * 128 * 4);       // 51.2 MB
    float* hfeat      = (float*)alloc((size_t)N_NODES * 64 * 4);        // 25.6 MB
    int*   bhist      = (int*)hfeat;   // alias: bhist (1.7 MB) dead before k_gat writes hfeat
    int*   bpack      = (int*)  alloc((size_t)E_TOT * 4);               // 4.4 MB
    int*   sorted_src = (int*)  alloc((size_t)E_TOT * 4);               // 4.4 MB
    int*   rowptr     = (int*)  alloc((size_t)(N_NODES + 1) * 4);
    int*   colsum     = (int*)  alloc((size_t)NB * 4);
    int*   colbase    = (int*)  alloc((size_t)(NB + 1) * 4);
    float* tbuf       = (float*)alloc((size_t)N_NODES * 4);
    float* rbuf       = (float*)alloc((size_t)N_NODES * 4);
    float* score      = (float*)alloc((size_t)N_NODES * 4);
    int*   start      = (int*)  alloc((size_t)(N_GRAPHS + 1) * 4);

    k_gemm            <<<GEMM_BLOCKS, 256, 0, stream>>>(x, Wl, Wr, xlr);
    k_bhist           <<<EB, 256, 0, stream>>>(ei, bhist);
    k_colprefix_bounds<<<CPW_BLOCKS + NODE_BLOCKS, 256, 0, stream>>>(bhist, colsum, batch, start);
    k_cbscan          <<<1, 256, 0, stream>>>(colsum, colbase);
    k_bscatter        <<<EB, 256, 0, stream>>>(ei, bhist, colbase, bpack);
    k_fine            <<<NB, 256, 0, stream>>>(bpack, colbase, rowptr, sorted_src);
    k_gat             <<<(N_NODES + 3) / 4, 256, 0, stream>>>(xlr, rowptr, sorted_src, att, bias,
                                                              w_rel, w_root, hfeat, tbuf, rbuf);
    k_pool            <<<N_GRAPHS, 256, 0, stream>>>(rowptr, sorted_src, tbuf, rbuf, b_sc,
                                                     score, hfeat, start, (float*)d_out);
}

// Round 13
// 239.003 us; speedup vs baseline: 1.6085x; 1.0205x over previous
//
#include <hip/hip_runtime.h>
#include <hip/hip_bf16.h>

#define N_NODES 100000
#define N_EDGES 1000000
#define N_GRAPHS 2048
#define F_IN 128
#define NEG_SLOPE 0.2f
#define E_TOT (N_EDGES + N_NODES)       // edges + self-loops
#define GEMM_BLOCKS 782                 // ceil(100000/128)
#define NODE_BLOCKS 391                 // ceil(100000/256)
#define NB 1563                         // coarse buckets = ceil(N_NODES/64)
#define EB 269                          // edge blocks = ceil(E_TOT/4096)
#define EB_PAD 272
#define CPW_BLOCKS 391                  // ceil(NB/4) wave-per-bucket scan blocks
#define SLDS_CAP 1088                   // per-bucket edge cap (mean 704, 6sigma~860)

typedef short  bf16x8 __attribute__((ext_vector_type(8)));
typedef float  f32x16 __attribute__((ext_vector_type(16)));

__device__ __forceinline__ short f2bf(float f) {      // RNE f32 -> bf16 bits
    unsigned u = __float_as_uint(f);
    unsigned r = (u + 0x7fffu + ((u >> 16) & 1u)) >> 16;
    return (short)r;
}
__device__ __forceinline__ float bf2f(short h) {
    return __uint_as_float(((unsigned)(unsigned short)h) << 16);
}

// ---- DPP helpers (ctrl is a template constant) ------------------------------
template <int CTRL>
__device__ __forceinline__ float dpp_add(float x) {
    return x + __int_as_float(__builtin_amdgcn_update_dpp(
        0, __float_as_int(x), CTRL, 0xf, 0xf, true));
}
__device__ __forceinline__ float head_sum_bcast(float x) {
    x = dpp_add<0x111>(x);   // row_shr:1
    x = dpp_add<0x112>(x);   // row_shr:2
    x = dpp_add<0x114>(x);   // row_shr:4
    x = dpp_add<0x118>(x);   // row_shr:8
    x = dpp_add<0x142>(x);   // row_bcast:15
    return __int_as_float(__builtin_amdgcn_ds_swizzle(__float_as_int(x), 0x03E0));
}
__device__ __forceinline__ float full_sum64(float x) {
    x = dpp_add<0x111>(x);
    x = dpp_add<0x112>(x);
    x = dpp_add<0x114>(x);
    x = dpp_add<0x118>(x);
    x = dpp_add<0x142>(x);   // row_bcast:15
    x = dpp_add<0x143>(x);   // row_bcast:31
    return x;
}
__device__ __forceinline__ float quad_sum(float x) {
    x = dpp_add<0xB1>(x);    // quad_perm [1,0,3,2]
    x = dpp_add<0x4E>(x);    // quad_perm [2,3,0,1]
    return x;
}

// ========== K1: xlr = x @ [W_l|W_r] (split-bf16 MFMA)  +  coarse histogram ====
__global__ __launch_bounds__(256) void k_gemm_bhist(const float* __restrict__ x,
                                                    const float* __restrict__ Wl,
                                                    const float* __restrict__ Wr,
                                                    const int* __restrict__ ei,
                                                    float* __restrict__ xlr,
                                                    int* __restrict__ bhist) {
    __shared__ unsigned char smem[2 * 128 * 136 * 2];   // overlaid: wt | lh
    int tid = threadIdx.x;
    if (blockIdx.x >= GEMM_BLOCKS) {            // -------- histogram part
        int* lh = (int*)smem;
        int b = blockIdx.x - GEMM_BLOCKS;
        for (int i = tid; i < NB; i += 256) lh[i] = 0;
        __syncthreads();
        int e0 = b * 4096;
#pragma unroll
        for (int j = 0; j < 16; ++j) {
            int e = e0 + j * 256 + tid;
            if (e < E_TOT) {
                int d = (e < N_EDGES) ? ei[N_EDGES + e] : (e - N_EDGES);
                atomicAdd(&lh[d >> 6], 1);
            }
        }
        __syncthreads();
        for (int i = tid; i < NB; i += 256)
            bhist[(size_t)i * EB_PAD + b] = lh[i];  // bucket-major
        return;
    }
    typedef short wt_t[128][136];
    wt_t* wt = (wt_t*)smem;                     // [hi/lo][n][k], +8 bf16 pad
    {   // ---- stage W transposed + split (once) ----
        int k  = tid >> 1;                      // 0..127
        int cq = tid & 1;                       // 0: cols 0-63 (Wl), 1: 64-127 (Wr)
        const float* Wsrc = cq ? Wr : Wl;
#pragma unroll
        for (int u = 0; u < 16; ++u) {
            int c0 = u * 4;
            float4 wv = *(const float4*)(Wsrc + (size_t)k * 64 + c0);
            float vv[4] = {wv.x, wv.y, wv.z, wv.w};
#pragma unroll
            for (int q = 0; q < 4; ++q) {
                int c = cq * 64 + c0 + q;
                short hi = f2bf(vv[q]);
                wt[0][c][k] = hi;
                wt[1][c][k] = f2bf(vv[q] - bf2f(hi));
            }
        }
    }
    __syncthreads();
    int lane = tid & 63, w = tid >> 6;
    int m = lane & 31, half = lane >> 5;
    int row = blockIdx.x * 128 + w * 32 + m;
    bool rv = row < N_NODES;
    const float* xrow = x + (size_t)(rv ? row : 0) * F_IN;
    f32x16 acc[4];
#pragma unroll
    for (int t = 0; t < 4; ++t)
#pragma unroll
        for (int i = 0; i < 16; ++i) acc[t][i] = 0.f;

#pragma unroll
    for (int kt = 0; kt < 8; ++kt) {            // K=16 steps
        int kb = kt * 16 + half * 8;
        float4 xa = rv ? *(const float4*)(xrow + kb)
                       : make_float4(0.f, 0.f, 0.f, 0.f);
        float4 xb = rv ? *(const float4*)(xrow + kb + 4)
                       : make_float4(0.f, 0.f, 0.f, 0.f);
        float xs[8] = {xa.x, xa.y, xa.z, xa.w, xb.x, xb.y, xb.z, xb.w};
        bf16x8 ahi, alo;
#pragma unroll
        for (int j = 0; j < 8; ++j) {
            short hi = f2bf(xs[j]);
            ahi[j] = hi;
            alo[j] = f2bf(xs[j] - bf2f(hi));
        }
#pragma unroll
        for (int t = 0; t < 4; ++t) {
            int n = t * 32 + m;
            bf16x8 bhi = *(const bf16x8*)&wt[0][n][kb];
            bf16x8 blo = *(const bf16x8*)&wt[1][n][kb];
            acc[t] = __builtin_amdgcn_mfma_f32_32x32x16_bf16(ahi, bhi, acc[t], 0, 0, 0);
            acc[t] = __builtin_amdgcn_mfma_f32_32x32x16_bf16(ahi, blo, acc[t], 0, 0, 0);
            acc[t] = __builtin_amdgcn_mfma_f32_32x32x16_bf16(alo, bhi, acc[t], 0, 0, 0);
        }
    }
    int r0 = blockIdx.x * 128 + w * 32 + 4 * half;
#pragma unroll
    for (int t = 0; t < 4; ++t)
#pragma unroll
        for (int reg = 0; reg < 16; ++reg) {
            int rr = r0 + (reg & 3) + 8 * (reg >> 2);
            if (rr < N_NODES)
                xlr[(size_t)rr * 128 + t * 32 + m] = acc[t][reg];
        }
}

// ========== K2: wave-per-bucket exclusive scan over blocks + bounds ===========
__global__ __launch_bounds__(256) void k_colprefix_bounds(int* __restrict__ bhist,
                                                          int* __restrict__ colsum,
                                                          const int* __restrict__ batch,
                                                          int* __restrict__ start) {
    if (blockIdx.x < CPW_BLOCKS) {
        int wv = blockIdx.x * 4 + (threadIdx.x >> 6);   // bucket id, wave-uniform
        if (wv >= NB) return;
        int lane = threadIdx.x & 63;
        int* row = bhist + (size_t)wv * EB_PAD;
        int carry = 0;
        for (int base = 0; base < EB; base += 64) {
            int idx = base + lane;
            int v = (idx < EB) ? row[idx] : 0;
            int inc = v;
#pragma unroll
            for (int o = 1; o < 64; o <<= 1) {
                int t = __shfl_up(inc, o, 64);
                if (lane >= o) inc += t;
            }
            int tot = __shfl(inc, 63, 64);
            if (idx < EB) row[idx] = carry + inc - v;   // exclusive prefix
            carry += tot;
        }
        if (lane == 0) colsum[wv] = carry;
    } else {
        int i = (blockIdx.x - CPW_BLOCKS) * 256 + threadIdx.x;
        if (i >= N_NODES) return;
        int bi = batch[i];
        int bp = (i == 0) ? -1 : batch[i - 1];
        for (int g = bp + 1; g <= bi; ++g) start[g] = i;
        if (i == N_NODES - 1)
            for (int g = bi + 1; g <= N_GRAPHS; ++g) start[g] = N_NODES;
    }
}

// ========== K3: scatter edges into coarse buckets; redundant colbase scan =====
__global__ __launch_bounds__(256) void k_bscatter(const int* __restrict__ ei,
                                                  const int* __restrict__ bhist,
                                                  const int* __restrict__ colsum,
                                                  int* __restrict__ colbase,
                                                  int* __restrict__ bpack) {
    __shared__ int lh[NB];
    __shared__ int cb[NB + 1];
    __shared__ int sctmp[256];
    int tid = threadIdx.x, b = blockIdx.x;
    {   // redundant exclusive scan of colsum -> cb (per block, wall-hidden)
        int v[7]; int s = 0;
#pragma unroll
        for (int k = 0; k < 7; ++k) {
            int idx = tid * 7 + k;
            v[k] = (idx < NB) ? colsum[idx] : 0;
            s += v[k];
        }
        sctmp[tid] = s; __syncthreads();
        for (int off = 1; off < 256; off <<= 1) {
            int xv = (tid >= off) ? sctmp[tid - off] : 0;
            __syncthreads();
            sctmp[tid] += xv;
            __syncthreads();
        }
        int run = sctmp[tid] - s;
#pragma unroll
        for (int k = 0; k < 7; ++k) {
            int idx = tid * 7 + k;
            if (idx <= NB) cb[idx] = run;
            run += v[k];
        }
    }
    for (int i = tid; i < NB; i += 256) lh[i] = 0;
    __syncthreads();
    if (b == 0)                                 // publish colbase for k_gatfine
        for (int i = tid; i <= NB; i += 256) colbase[i] = cb[i];
    int e0 = b * 4096;
#pragma unroll
    for (int j = 0; j < 16; ++j) {
        int e = e0 + j * 256 + tid;
        if (e < E_TOT) {
            int s, d;
            if (e < N_EDGES) { s = ei[e]; d = ei[N_EDGES + e]; }
            else             { s = d = e - N_EDGES; }
            int bk = d >> 6;
            int lr = atomicAdd(&lh[bk], 1);
            int pos = cb[bk] + bhist[(size_t)bk * EB_PAD + b] + lr;
            bpack[pos] = s | ((d & 63) << 17);  // src in 17 bits, local dst in 6
        }
    }
}

// ========== K4: fused fine-grouping + GATv2 (block per 64-dst bucket) =========
__global__ __launch_bounds__(256) void k_gatfine(const float* __restrict__ xlr,
                                                 const int* __restrict__ bpack,
                                                 const int* __restrict__ colbase,
                                                 const float* __restrict__ att,
                                                 const float* __restrict__ bias,
                                                 const float* __restrict__ w_rel,
                                                 const float* __restrict__ w_root,
                                                 int* __restrict__ rowptr,
                                                 int* __restrict__ sorted_src,
                                                 float* __restrict__ hfeat,
                                                 float* __restrict__ tbuf,
                                                 float* __restrict__ rbuf) {
    __shared__ int lrp[65];
    __shared__ int fcnt[64];
    __shared__ int foff[64];
    __shared__ int slds[SLDS_CAP];
    int bi = blockIdx.x, tid = threadIdx.x;
    int cb0 = colbase[bi], cb1 = colbase[bi + 1];
    int cnt = cb1 - cb0;
    if (tid < 64) fcnt[tid] = 0;
    __syncthreads();
    for (int e = tid; e < cnt; e += 256)
        atomicAdd(&fcnt[bpack[cb0 + e] >> 17], 1);
    __syncthreads();
    if (tid < 64) {                             // wave 0: scan of 64 counts
        int v = fcnt[tid];
        int inc = v;
#pragma unroll
        for (int o = 1; o < 64; o <<= 1) {
            int t = __shfl_up(inc, o, 64);
            if (tid >= o) inc += t;
        }
        int excl = inc - v;
        foff[tid] = excl;
        lrp[tid] = excl;
        if (tid == 63) lrp[64] = inc;
        int node = bi * 64 + tid;
        if (node <= N_NODES) rowptr[node] = cb0 + excl;   // for k_pool
    }
    __syncthreads();
    for (int e = tid; e < cnt; e += 256) {
        int w = bpack[cb0 + e];
        int lr = atomicAdd(&foff[w >> 17], 1);
        int s = w & 131071;
        slds[lr] = s;
        sorted_src[cb0 + lr] = s;               // for k_pool
    }
    __syncthreads();
    // ---- GAT: wave wv processes local dsts wv*16 .. wv*16+15 -----------------
    int lane = tid & 63, wv = tid >> 6;
    float att_l  = att[lane];
    float bias_l = bias[lane];
    float wrel_l = w_rel[lane];
    float wroot_l = w_root[lane];
    for (int q = 0; q < 16; ++q) {
        int dl = wv * 16 + q;
        int du = bi * 64 + dl;
        if (du >= N_NODES) break;
        int j0 = __builtin_amdgcn_readfirstlane(lrp[dl]);
        int j1 = __builtin_amdgcn_readfirstlane(lrp[dl + 1]);
        float xr_l = xlr[(size_t)du * 128 + 64 + lane];
        float wsum = 0.f, acc = 0.f;
        int jc = j0;
        for (; jc + 8 <= j1; jc += 8) {         // full chunks of 8
            int sv = slds[jc + (lane & 7)];
            float p[8], xv[8];
#pragma unroll
            for (int i = 0; i < 8; ++i) {
                int s = __builtin_amdgcn_readlane(sv, i);
                xv[i] = (xlr + (size_t)(unsigned)s * 128)[lane];
            }
#pragma unroll
            for (int i = 0; i < 8; ++i) {
                float v = xv[i] + xr_l;
                v = (v > 0.f) ? v : NEG_SLOPE * v;
                p[i] = v * att_l;
            }
#pragma unroll
            for (int i = 0; i < 8; ++i)
                p[i] = head_sum_bcast(p[i]);
#pragma unroll
            for (int i = 0; i < 8; ++i) {
                float w = __expf(p[i]);         // logits bounded; no max needed
                wsum += w;
                acc += w * xv[i];
            }
        }
        for (; jc < j1; jc += 4) {              // masked chunks of 4
            int n = j1 - jc;
            int jj = jc + (lane & 3);
            if (jj > j1 - 1) jj = j1 - 1;
            int sv = slds[jj];
            float p[4], xv[4];
#pragma unroll
            for (int i = 0; i < 4; ++i) {
                int s = __builtin_amdgcn_readlane(sv, i);
                xv[i] = (xlr + (size_t)(unsigned)s * 128)[lane];
            }
#pragma unroll
            for (int i = 0; i < 4; ++i) {
                float v = xv[i] + xr_l;
                v = (v > 0.f) ? v : NEG_SLOPE * v;
                p[i] = v * att_l;
            }
#pragma unroll
            for (int i = 0; i < 4; ++i)
                p[i] = head_sum_bcast(p[i]);
#pragma unroll
            for (int i = 0; i < 4; ++i) {
                float w = (i < n) ? __expf(p[i]) : 0.f;
                wsum += w;
                acc += w * xv[i];
            }
        }
        float h = acc / wsum + bias_l;
        hfeat[(size_t)du * 64 + lane] = h;
        float a = full_sum64(h * wrel_l);
        float b = full_sum64(h * wroot_l);
        if (lane == 63) { tbuf[du] = a; rbuf[du] = b; }
    }
}

// ========== K5: fused score + per-graph softmax-pool (block per graph) ========
__global__ __launch_bounds__(256) void k_pool(const int* __restrict__ rowptr,
                                              const int* __restrict__ sorted_src,
                                              const float* __restrict__ t,
                                              const float* __restrict__ r,
                                              const float* __restrict__ b_score,
                                              float* __restrict__ score,
                                              const float* __restrict__ h,
                                              const int* __restrict__ start,
                                              float* __restrict__ out) {
    __shared__ float sh[4];
    __shared__ float shacc[4][64];
    int g = blockIdx.x;
    int tid = threadIdx.x, w = tid >> 6, lane = tid & 63;
    int n0 = start[g], n1 = start[g + 1];
    int cnt = n1 - n0;
    if (cnt <= 0) { if (tid < 64) out[(size_t)g * 64 + tid] = 0.f; return; }
    float bsc = b_score[0];
    // --- phase 1: scores via sorted CSR, 4 threads per node + quad reduce
    for (int base = n0; base < n1; base += 64) {
        int i = base + (tid >> 2);
        float sum = 0.f;
        int jj0 = 0, jj1 = 0;
        if (i < n1) { jj0 = rowptr[i]; jj1 = rowptr[i + 1]; }
        for (int j = jj0 + (tid & 3); j < jj1; j += 4)
            sum += t[sorted_src[j]];
        sum = quad_sum(sum);
        if (i < n1 && (tid & 3) == 0)
            score[i] = sum - t[i] + r[i] + bsc;
    }
    __syncthreads();
    // --- phase 2a: max, then overwrite score with exp(score-m); sum exps
    float m = -1e30f;
    for (int i = n0 + tid; i < n1; i += 256) m = fmaxf(m, score[i]);
#pragma unroll
    for (int o = 32; o; o >>= 1) m = fmaxf(m, __shfl_xor(m, o, 64));
    if (lane == 0) sh[w] = m;
    __syncthreads();
    m = fmaxf(fmaxf(sh[0], sh[1]), fmaxf(sh[2], sh[3]));
    __syncthreads();
    float ssum = 0.f;
    for (int i = n0 + tid; i < n1; i += 256) {
        float e = __expf(score[i] - m);
        score[i] = e;
        ssum += e;
    }
#pragma unroll
    for (int o = 32; o; o >>= 1) ssum += __shfl_xor(ssum, o, 64);
    if (lane == 0) sh[w] = ssum;
    __syncthreads();
    ssum = sh[0] + sh[1] + sh[2] + sh[3];
    // --- phase 2b: weighted feature accumulation (no redundant exps)
    float acc = 0.f;
    for (int i = n0 + w; i < n1; i += 4)
        acc += score[i] * h[(size_t)i * 64 + lane];
    shacc[w][lane] = acc;
    __syncthreads();
    if (w == 0) {
        float tot = shacc[0][lane] + shacc[1][lane] + shacc[2][lane] + shacc[3][lane];
        out[(size_t)g * 64 + lane] = tot * (1.f + 1.f / (float)cnt) / ssum;
    }
}

extern "C" void kernel_launch(void* const* d_in, const int* in_sizes, int n_in,
                              void* d_out, int out_size, void* d_ws, size_t ws_size,
                              hipStream_t stream) {
    const float* x      = (const float*)d_in[0];
    const int*   ei     = (const int*)d_in[1];
    const int*   batch  = (const int*)d_in[2];
    const float* Wl     = (const float*)d_in[3];
    const float* Wr     = (const float*)d_in[4];
    const float* att    = (const float*)d_in[5];
    const float* bias   = (const float*)d_in[6];
    const float* w_rel  = (const float*)d_in[7];
    const float* w_root = (const float*)d_in[8];
    const float* b_sc   = (const float*)d_in[9];

    char* ws = (char*)d_ws;
    size_t off = 0;
    auto alloc = [&](size_t bytes) { void* p = ws + off; off += (bytes + 255) & ~255ull; return p; };
    float* xlr        = (float*)alloc((size_t)N_NODES * 128 * 4);       // 51.2 MB
    float* hfeat      = (float*)alloc((size_t)N_NODES * 64 * 4);        // 25.6 MB
    int*   bhist      = (int*)hfeat;   // alias: bhist (1.7 MB) dead before k_gatfine writes hfeat
    int*   bpack      = (int*)  alloc((size_t)E_TOT * 4);               // 4.4 MB
    int*   sorted_src = (int*)  alloc((size_t)E_TOT * 4);               // 4.4 MB
    int*   rowptr     = (int*)  alloc((size_t)(N_NODES + 1) * 4);
    int*   colsum     = (int*)  alloc((size_t)NB * 4);
    int*   colbase    = (int*)  alloc((size_t)(NB + 1) * 4);
    float* tbuf       = (float*)alloc((size_t)N_NODES * 4);
    float* rbuf       = (float*)alloc((size_t)N_NODES * 4);
    float* score      = (float*)alloc((size_t)N_NODES * 4);
    int*   start      = (int*)  alloc((size_t)(N_GRAPHS + 1) * 4);

    k_gemm_bhist      <<<GEMM_BLOCKS + EB, 256, 0, stream>>>(x, Wl, Wr, ei, xlr, bhist);
    k_colprefix_bounds<<<CPW_BLOCKS + NODE_BLOCKS, 256, 0, stream>>>(bhist, colsum, batch, start);
    k_bscatter        <<<EB, 256, 0, stream>>>(ei, bhist, colsum, colbase, bpack);
    k_gatfine         <<<NB, 256, 0, stream>>>(xlr, bpack, colbase, att, bias, w_rel, w_root,
                                               rowptr, sorted_src, hfeat, tbuf, rbuf);
    k_pool            <<<N_GRAPHS, 256, 0, stream>>>(rowptr, sorted_src, tbuf, rbuf, b_sc,
                                                     score, hfeat, start, (float*)d_out);
}

// Round 14
// 238.004 us; speedup vs baseline: 1.6152x; 1.0042x over previous
//
#include <hip/hip_runtime.h>
#include <hip/hip_bf16.h>

#define N_NODES 100000
#define N_EDGES 1000000
#define N_GRAPHS 2048
#define F_IN 128
#define NEG_SLOPE 0.2f
#define E_TOT (N_EDGES + N_NODES)       // edges + self-loops
#define GEMM_BLOCKS 782                 // ceil(100000/128)
#define NODE_BLOCKS 391                 // ceil(100000/256)
#define NB 1563                         // coarse buckets = ceil(N_NODES/64)
#define EB 269                          // edge blocks = ceil(E_TOT/4096)
#define EB_PAD 272
#define CPW_BLOCKS 391                  // ceil(NB/4) wave-per-bucket scan blocks

typedef short  bf16x8 __attribute__((ext_vector_type(8)));
typedef float  f32x16 __attribute__((ext_vector_type(16)));

__device__ __forceinline__ short f2bf(float f) {      // RNE f32 -> bf16 bits
    unsigned u = __float_as_uint(f);
    unsigned r = (u + 0x7fffu + ((u >> 16) & 1u)) >> 16;
    return (short)r;
}
__device__ __forceinline__ float bf2f(short h) {
    return __uint_as_float(((unsigned)(unsigned short)h) << 16);
}

// ---- DPP helpers (ctrl is a template constant) ------------------------------
template <int CTRL>
__device__ __forceinline__ float dpp_add(float x) {
    return x + __int_as_float(__builtin_amdgcn_update_dpp(
        0, __float_as_int(x), CTRL, 0xf, 0xf, true));
}
__device__ __forceinline__ float head_sum_bcast(float x) {
    x = dpp_add<0x111>(x);   // row_shr:1
    x = dpp_add<0x112>(x);   // row_shr:2
    x = dpp_add<0x114>(x);   // row_shr:4
    x = dpp_add<0x118>(x);   // row_shr:8
    x = dpp_add<0x142>(x);   // row_bcast:15
    return __int_as_float(__builtin_amdgcn_ds_swizzle(__float_as_int(x), 0x03E0));
}
__device__ __forceinline__ float full_sum64(float x) {
    x = dpp_add<0x111>(x);
    x = dpp_add<0x112>(x);
    x = dpp_add<0x114>(x);
    x = dpp_add<0x118>(x);
    x = dpp_add<0x142>(x);   // row_bcast:15
    x = dpp_add<0x143>(x);   // row_bcast:31
    return x;
}
__device__ __forceinline__ float quad_sum(float x) {
    x = dpp_add<0xB1>(x);    // quad_perm [1,0,3,2]
    x = dpp_add<0x4E>(x);    // quad_perm [2,3,0,1]
    return x;
}

// ========== K1: xlr = x @ [W_l|W_r] (split-bf16 MFMA)  +  coarse histogram ====
__global__ __launch_bounds__(256) void k_gemm_bhist(const float* __restrict__ x,
                                                    const float* __restrict__ Wl,
                                                    const float* __restrict__ Wr,
                                                    const int* __restrict__ ei,
                                                    float* __restrict__ xlr,
                                                    int* __restrict__ bhist) {
    __shared__ unsigned char smem[2 * 128 * 136 * 2];   // overlaid: wt | lh
    int tid = threadIdx.x;
    if (blockIdx.x >= GEMM_BLOCKS) {            // -------- histogram part
        int* lh = (int*)smem;
        int b = blockIdx.x - GEMM_BLOCKS;
        for (int i = tid; i < NB; i += 256) lh[i] = 0;
        __syncthreads();
        int e0 = b * 4096;
#pragma unroll
        for (int j = 0; j < 16; ++j) {
            int e = e0 + j * 256 + tid;
            if (e < E_TOT) {
                int d = (e < N_EDGES) ? ei[N_EDGES + e] : (e - N_EDGES);
                atomicAdd(&lh[d >> 6], 1);
            }
        }
        __syncthreads();
        for (int i = tid; i < NB; i += 256)
            bhist[(size_t)i * EB_PAD + b] = lh[i];  // bucket-major
        return;
    }
    typedef short wt_t[128][136];
    wt_t* wt = (wt_t*)smem;                     // [hi/lo][n][k], +8 bf16 pad
    {   // ---- stage W transposed + split (once) ----
        int k  = tid >> 1;
        int cq = tid & 1;
        const float* Wsrc = cq ? Wr : Wl;
#pragma unroll
        for (int u = 0; u < 16; ++u) {
            int c0 = u * 4;
            float4 wv = *(const float4*)(Wsrc + (size_t)k * 64 + c0);
            float vv[4] = {wv.x, wv.y, wv.z, wv.w};
#pragma unroll
            for (int q = 0; q < 4; ++q) {
                int c = cq * 64 + c0 + q;
                short hi = f2bf(vv[q]);
                wt[0][c][k] = hi;
                wt[1][c][k] = f2bf(vv[q] - bf2f(hi));
            }
        }
    }
    __syncthreads();
    int lane = tid & 63, w = tid >> 6;
    int m = lane & 31, half = lane >> 5;
    int row = blockIdx.x * 128 + w * 32 + m;
    bool rv = row < N_NODES;
    const float* xrow = x + (size_t)(rv ? row : 0) * F_IN;
    f32x16 acc[4];
#pragma unroll
    for (int t = 0; t < 4; ++t)
#pragma unroll
        for (int i = 0; i < 16; ++i) acc[t][i] = 0.f;

#pragma unroll
    for (int kt = 0; kt < 8; ++kt) {            // K=16 steps
        int kb = kt * 16 + half * 8;
        float4 xa = rv ? *(const float4*)(xrow + kb)
                       : make_float4(0.f, 0.f, 0.f, 0.f);
        float4 xb = rv ? *(const float4*)(xrow + kb + 4)
                       : make_float4(0.f, 0.f, 0.f, 0.f);
        float xs[8] = {xa.x, xa.y, xa.z, xa.w, xb.x, xb.y, xb.z, xb.w};
        bf16x8 ahi, alo;
#pragma unroll
        for (int j = 0; j < 8; ++j) {
            short hi = f2bf(xs[j]);
            ahi[j] = hi;
            alo[j] = f2bf(xs[j] - bf2f(hi));
        }
#pragma unroll
        for (int t = 0; t < 4; ++t) {
            int n = t * 32 + m;
            bf16x8 bhi = *(const bf16x8*)&wt[0][n][kb];
            bf16x8 blo = *(const bf16x8*)&wt[1][n][kb];
            acc[t] = __builtin_amdgcn_mfma_f32_32x32x16_bf16(ahi, bhi, acc[t], 0, 0, 0);
            acc[t] = __builtin_amdgcn_mfma_f32_32x32x16_bf16(ahi, blo, acc[t], 0, 0, 0);
            acc[t] = __builtin_amdgcn_mfma_f32_32x32x16_bf16(alo, bhi, acc[t], 0, 0, 0);
        }
    }
    int r0 = blockIdx.x * 128 + w * 32 + 4 * half;
#pragma unroll
    for (int t = 0; t < 4; ++t)
#pragma unroll
        for (int reg = 0; reg < 16; ++reg) {
            int rr = r0 + (reg & 3) + 8 * (reg >> 2);
            if (rr < N_NODES)
                xlr[(size_t)rr * 128 + t * 32 + m] = acc[t][reg];
        }
}

// ========== K2: wave-per-bucket exclusive scan over blocks + bounds ===========
__global__ __launch_bounds__(256) void k_colprefix_bounds(int* __restrict__ bhist,
                                                          int* __restrict__ colsum,
                                                          const int* __restrict__ batch,
                                                          int* __restrict__ start) {
    if (blockIdx.x < CPW_BLOCKS) {
        int wv = blockIdx.x * 4 + (threadIdx.x >> 6);   // bucket id, wave-uniform
        if (wv >= NB) return;
        int lane = threadIdx.x & 63;
        int* row = bhist + (size_t)wv * EB_PAD;
        int carry = 0;
        for (int base = 0; base < EB; base += 64) {
            int idx = base + lane;
            int v = (idx < EB) ? row[idx] : 0;
            int inc = v;
#pragma unroll
            for (int o = 1; o < 64; o <<= 1) {
                int t = __shfl_up(inc, o, 64);
                if (lane >= o) inc += t;
            }
            int tot = __shfl(inc, 63, 64);
            if (idx < EB) row[idx] = carry + inc - v;   // exclusive prefix
            carry += tot;
        }
        if (lane == 0) colsum[wv] = carry;
    } else {
        int i = (blockIdx.x - CPW_BLOCKS) * 256 + threadIdx.x;
        if (i >= N_NODES) return;
        int bi = batch[i];
        int bp = (i == 0) ? -1 : batch[i - 1];
        for (int g = bp + 1; g <= bi; ++g) start[g] = i;
        if (i == N_NODES - 1)
            for (int g = bi + 1; g <= N_GRAPHS; ++g) start[g] = N_NODES;
    }
}

// ========== K3: scatter edges into coarse buckets; redundant colbase scan =====
__global__ __launch_bounds__(256) void k_bscatter(const int* __restrict__ ei,
                                                  const int* __restrict__ bhist,
                                                  const int* __restrict__ colsum,
                                                  int* __restrict__ colbase,
                                                  int* __restrict__ bpack) {
    __shared__ int lh[NB];
    __shared__ int cb[NB + 1];
    __shared__ int sctmp[256];
    int tid = threadIdx.x, b = blockIdx.x;
    {   // redundant exclusive scan of colsum -> cb (per block, wall-hidden)
        int v[7]; int s = 0;
#pragma unroll
        for (int k = 0; k < 7; ++k) {
            int idx = tid * 7 + k;
            v[k] = (idx < NB) ? colsum[idx] : 0;
            s += v[k];
        }
        sctmp[tid] = s; __syncthreads();
        for (int off = 1; off < 256; off <<= 1) {
            int xv = (tid >= off) ? sctmp[tid - off] : 0;
            __syncthreads();
            sctmp[tid] += xv;
            __syncthreads();
        }
        int run = sctmp[tid] - s;
#pragma unroll
        for (int k = 0; k < 7; ++k) {
            int idx = tid * 7 + k;
            if (idx <= NB) cb[idx] = run;
            run += v[k];
        }
    }
    for (int i = tid; i < NB; i += 256) lh[i] = 0;
    __syncthreads();
    if (b == 0)                                 // publish colbase for k_fine
        for (int i = tid; i <= NB; i += 256) colbase[i] = cb[i];
    int e0 = b * 4096;
#pragma unroll
    for (int j = 0; j < 16; ++j) {
        int e = e0 + j * 256 + tid;
        if (e < E_TOT) {
            int s, d;
            if (e < N_EDGES) { s = ei[e]; d = ei[N_EDGES + e]; }
            else             { s = d = e - N_EDGES; }
            int bk = d >> 6;
            int lr = atomicAdd(&lh[bk], 1);
            int pos = cb[bk] + bhist[(size_t)bk * EB_PAD + b] + lr;
            bpack[pos] = s | ((d & 63) << 17);  // src in 17 bits, local dst in 6
        }
    }
}

// ========== K4: per-bucket fine grouping -> rowptr + sorted_src ===============
__global__ __launch_bounds__(256) void k_fine(const int* __restrict__ bpack,
                                              const int* __restrict__ colbase,
                                              int* __restrict__ rowptr,
                                              int* __restrict__ sorted_src) {
    __shared__ int fcnt[64];
    __shared__ int foff[64];
    int i = blockIdx.x, tid = threadIdx.x;
    int cb0 = colbase[i], cb1 = colbase[i + 1];
    if (tid < 64) fcnt[tid] = 0;
    __syncthreads();
    for (int e = cb0 + tid; e < cb1; e += 256)
        atomicAdd(&fcnt[bpack[e] >> 17], 1);
    __syncthreads();
    if (tid < 64) {                             // wave 0: scan of 64 counts
        int v = fcnt[tid];
        int inc = v;
#pragma unroll
        for (int o = 1; o < 64; o <<= 1) {
            int t = __shfl_up(inc, o, 64);
            if (tid >= o) inc += t;
        }
        int excl = inc - v;
        foff[tid] = excl;
        int node = i * 64 + tid;
        if (node <= N_NODES) rowptr[node] = cb0 + excl;
    }
    __syncthreads();
    for (int e = cb0 + tid; e < cb1; e += 256) {
        int w = bpack[e];
        int lr = atomicAdd(&foff[w >> 17], 1);
        sorted_src[cb0 + lr] = w & 131071;
    }
}

// ========== K5: GATv2 per dst — software-pipelined chunks (prefetch next) =====
__global__ __launch_bounds__(256) void k_gat(const float* __restrict__ xlr,
                                             const int* __restrict__ rowptr,
                                             const int* __restrict__ sorted_src,
                                             const float* __restrict__ att,
                                             const float* __restrict__ bias,
                                             const float* __restrict__ w_rel,
                                             const float* __restrict__ w_root,
                                             float* __restrict__ hfeat,
                                             float* __restrict__ tbuf,
                                             float* __restrict__ rbuf) {
    int lane = threadIdx.x & 63;
    int du = __builtin_amdgcn_readfirstlane(blockIdx.x * 4 + (threadIdx.x >> 6));
    if (du >= N_NODES) return;
    float xr_l  = xlr[(size_t)du * 128 + 64 + lane];
    float att_l = att[lane];
    int j0 = __builtin_amdgcn_readfirstlane(rowptr[du]);
    int j1 = __builtin_amdgcn_readfirstlane(rowptr[du + 1]);   // >= j0+1
    float wsum = 0.f, acc = 0.f;
    // ---- prologue: load chunk 0 ----
    int jc = j0;
    float xv[8];
    {
        int jj = jc + (lane & 7);
        if (jj > j1 - 1) jj = j1 - 1;
        int sv = sorted_src[jj];
#pragma unroll
        for (int i = 0; i < 8; ++i) {
            int s = __builtin_amdgcn_readlane(sv, i);
            xv[i] = (xlr + (size_t)(unsigned)s * 128)[lane];
        }
    }
    while (true) {
        int n = j1 - jc;                        // wave-uniform
        int jn = jc + 8;
        bool more = jn < j1;                    // wave-uniform
        float xvn[8];
        if (more) {                             // prefetch next chunk
            int jj = jn + (lane & 7);
            if (jj > j1 - 1) jj = j1 - 1;
            int sv = sorted_src[jj];
#pragma unroll
            for (int i = 0; i < 8; ++i) {
                int s = __builtin_amdgcn_readlane(sv, i);
                xvn[i] = (xlr + (size_t)(unsigned)s * 128)[lane];
            }
        }
        // ---- compute current chunk ----
        float p[8];
#pragma unroll
        for (int i = 0; i < 8; ++i) {
            float v = xv[i] + xr_l;
            v = (v > 0.f) ? v : NEG_SLOPE * v;
            p[i] = v * att_l;
        }
#pragma unroll
        for (int i = 0; i < 8; ++i)
            p[i] = head_sum_bcast(p[i]);
        if (n >= 8) {                           // unmasked (wave-uniform branch)
#pragma unroll
            for (int i = 0; i < 8; ++i) {
                float w = __expf(p[i]);         // logits bounded; no max needed
                wsum += w;
                acc += w * xv[i];
            }
        } else {                                // masked tail
#pragma unroll
            for (int i = 0; i < 8; ++i) {
                float w = (i < n) ? __expf(p[i]) : 0.f;
                wsum += w;
                acc += w * xv[i];
            }
        }
        if (!more) break;
        jc = jn;
#pragma unroll
        for (int i = 0; i < 8; ++i) xv[i] = xvn[i];
    }
    float h = acc / wsum + bias[lane];
    hfeat[(size_t)du * 64 + lane] = h;
    float a = full_sum64(h * w_rel[lane]);
    float b = full_sum64(h * w_root[lane]);
    if (lane == 63) { tbuf[du] = a; rbuf[du] = b; }
}

// ========== K6: fused score + per-graph softmax-pool (block per graph) ========
__global__ __launch_bounds__(256) void k_pool(const int* __restrict__ rowptr,
                                              const int* __restrict__ sorted_src,
                                              const float* __restrict__ t,
                                              const float* __restrict__ r,
                                              const float* __restrict__ b_score,
                                              float* __restrict__ score,
                                              const float* __restrict__ h,
                                              const int* __restrict__ start,
                                              float* __restrict__ out) {
    __shared__ float sh[4];
    __shared__ float shacc[4][64];
    int g = blockIdx.x;
    int tid = threadIdx.x, w = tid >> 6, lane = tid & 63;
    int n0 = start[g], n1 = start[g + 1];
    int cnt = n1 - n0;
    if (cnt <= 0) { if (tid < 64) out[(size_t)g * 64 + tid] = 0.f; return; }
    float bsc = b_score[0];
    // --- phase 1: scores via sorted CSR, 4 threads per node + quad reduce
    for (int base = n0; base < n1; base += 64) {
        int i = base + (tid >> 2);
        float sum = 0.f;
        int jj0 = 0, jj1 = 0;
        if (i < n1) { jj0 = rowptr[i]; jj1 = rowptr[i + 1]; }
        for (int j = jj0 + (tid & 3); j < jj1; j += 4)
            sum += t[sorted_src[j]];
        sum = quad_sum(sum);
        if (i < n1 && (tid & 3) == 0)
            score[i] = sum - t[i] + r[i] + bsc;
    }
    __syncthreads();
    // --- phase 2a: max, then overwrite score with exp(score-m); sum exps
    float m = -1e30f;
    for (int i = n0 + tid; i < n1; i += 256) m = fmaxf(m, score[i]);
#pragma unroll
    for (int o = 32; o; o >>= 1) m = fmaxf(m, __shfl_xor(m, o, 64));
    if (lane == 0) sh[w] = m;
    __syncthreads();
    m = fmaxf(fmaxf(sh[0], sh[1]), fmaxf(sh[2], sh[3]));
    __syncthreads();
    float ssum = 0.f;
    for (int i = n0 + tid; i < n1; i += 256) {
        float e = __expf(score[i] - m);
        score[i] = e;
        ssum += e;
    }
#pragma unroll
    for (int o = 32; o; o >>= 1) ssum += __shfl_xor(ssum, o, 64);
    if (lane == 0) sh[w] = ssum;
    __syncthreads();
    ssum = sh[0] + sh[1] + sh[2] + sh[3];
    // --- phase 2b: weighted feature accumulation (no redundant exps)
    float acc = 0.f;
    for (int i = n0 + w; i < n1; i += 4)
        acc += score[i] * h[(size_t)i * 64 + lane];
    shacc[w][lane] = acc;
    __syncthreads();
    if (w == 0) {
        float tot = shacc[0][lane] + shacc[1][lane] + shacc[2][lane] + shacc[3][lane];
        out[(size_t)g * 64 + lane] = tot * (1.f + 1.f / (float)cnt) / ssum;
    }
}

extern "C" void kernel_launch(void* const* d_in, const int* in_sizes, int n_in,
                              void* d_out, int out_size, void* d_ws, size_t ws_size,
                              hipStream_t stream) {
    const float* x      = (const float*)d_in[0];
    const int*   ei     = (const int*)d_in[1];
    const int*   batch  = (const int*)d_in[2];
    const float* Wl     = (const float*)d_in[3];
    const float* Wr     = (const float*)d_in[4];
    const float* att    = (const float*)d_in[5];
    const float* bias   = (const float*)d_in[6];
    const float* w_rel  = (const float*)d_in[7];
    const float* w_root = (const float*)d_in[8];
    const float* b_sc   = (const float*)d_in[9];

    char* ws = (char*)d_ws;
    size_t off = 0;
    auto alloc = [&](size_t bytes) { void* p = ws + off; off += (bytes + 255) & ~255ull; return p; };
    float* xlr        = (float*)alloc((size_t)N_NODES * 128 * 4);       // 51.2 MB
    float* hfeat      = (float*)alloc((size_t)N_NODES * 64 * 4);        // 25.6 MB
    int*   bhist      = (int*)hfeat;   // alias: bhist dead before k_gat writes hfeat
    int*   bpack      = (int*)  alloc((size_t)E_TOT * 4);               // 4.4 MB
    int*   sorted_src = (int*)  alloc((size_t)E_TOT * 4);               // 4.4 MB
    int*   rowptr     = (int*)  alloc((size_t)(N_NODES + 1) * 4);
    int*   colsum     = (int*)  alloc((size_t)NB * 4);
    int*   colbase    = (int*)  alloc((size_t)(NB + 1) * 4);
    float* tbuf       = (float*)alloc((size_t)N_NODES * 4);
    float* rbuf       = (float*)alloc((size_t)N_NODES * 4);
    float* score      = (float*)alloc((size_t)N_NODES * 4);
    int*   start      = (int*)  alloc((size_t)(N_GRAPHS + 1) * 4);

    k_gemm_bhist      <<<GEMM_BLOCKS + EB, 256, 0, stream>>>(x, Wl, Wr, ei, xlr, bhist);
    k_colprefix_bounds<<<CPW_BLOCKS + NODE_BLOCKS, 256, 0, stream>>>(bhist, colsum, batch, start);
    k_bscatter        <<<EB, 256, 0, stream>>>(ei, bhist, colsum, colbase, bpack);
    k_fine            <<<NB, 256, 0, stream>>>(bpack, colbase, rowptr, sorted_src);
    k_gat             <<<(N_NODES + 3) / 4, 256, 0, stream>>>(xlr, rowptr, sorted_src, att, bias,
                                                              w_rel, w_root, hfeat, tbuf, rbuf);
    k_pool            <<<N_GRAPHS, 256, 0, stream>>>(rowptr, sorted_src, tbuf, rbuf, b_sc,
                                                     score, hfeat, start, (float*)d_out);
}

// Round 15
// 229.845 us; speedup vs baseline: 1.6725x; 1.0355x over previous
//
#include <hip/hip_runtime.h>
#include <hip/hip_bf16.h>

#define N_NODES 100000
#define N_EDGES 1000000
#define N_GRAPHS 2048
#define F_IN 128
#define NEG_SLOPE 0.2f
#define E_TOT (N_EDGES + N_NODES)       // edges + self-loops
#define GEMM_BLOCKS 782                 // ceil(100000/128)
#define NODE_BLOCKS 391                 // ceil(100000/256)
#define NB 1563                         // coarse buckets = ceil(N_NODES/64)
#define EB 269                          // edge blocks = ceil(E_TOT/4096)
#define EB_PAD 272
#define CPW_BLOCKS 391                  // ceil(NB/4) wave-per-bucket scan blocks

typedef short  bf16x8 __attribute__((ext_vector_type(8)));
typedef float  f32x16 __attribute__((ext_vector_type(16)));

__device__ __forceinline__ short f2bf(float f) {      // RNE f32 -> bf16 bits
    unsigned u = __float_as_uint(f);
    unsigned r = (u + 0x7fffu + ((u >> 16) & 1u)) >> 16;
    return (short)r;
}
__device__ __forceinline__ float bf2f(short h) {
    return __uint_as_float(((unsigned)(unsigned short)h) << 16);
}

// ---- DPP helpers (ctrl is a template constant) ------------------------------
template <int CTRL>
__device__ __forceinline__ float dpp_add(float x) {
    return x + __int_as_float(__builtin_amdgcn_update_dpp(
        0, __float_as_int(x), CTRL, 0xf, 0xf, true));
}
__device__ __forceinline__ float full_sum64(float x) {
    x = dpp_add<0x111>(x);
    x = dpp_add<0x112>(x);
    x = dpp_add<0x114>(x);
    x = dpp_add<0x118>(x);
    x = dpp_add<0x142>(x);   // row_bcast:15
    x = dpp_add<0x143>(x);   // row_bcast:31
    return x;
}
__device__ __forceinline__ float quad_sum(float x) {
    x = dpp_add<0xB1>(x);    // quad_perm [1,0,3,2]
    x = dpp_add<0x4E>(x);    // quad_perm [2,3,0,1]
    return x;
}

// ========== K1: xr/xlb = x @ [W_l|W_r] (split-bf16 MFMA)  +  coarse hist ======
__global__ __launch_bounds__(256) void k_gemm_bhist(const float* __restrict__ x,
                                                    const float* __restrict__ Wl,
                                                    const float* __restrict__ Wr,
                                                    const int* __restrict__ ei,
                                                    float* __restrict__ xr,
                                                    short* __restrict__ xlb,
                                                    int* __restrict__ bhist) {
    __shared__ unsigned char smem[2 * 128 * 136 * 2];   // overlaid: wt | lh
    int tid = threadIdx.x;
    if (blockIdx.x >= GEMM_BLOCKS) {            // -------- histogram part
        int* lh = (int*)smem;
        int b = blockIdx.x - GEMM_BLOCKS;
        for (int i = tid; i < NB; i += 256) lh[i] = 0;
        __syncthreads();
        int e0 = b * 4096;
#pragma unroll
        for (int j = 0; j < 16; ++j) {
            int e = e0 + j * 256 + tid;
            if (e < E_TOT) {
                int d = (e < N_EDGES) ? ei[N_EDGES + e] : (e - N_EDGES);
                atomicAdd(&lh[d >> 6], 1);
            }
        }
        __syncthreads();
        for (int i = tid; i < NB; i += 256)
            bhist[(size_t)i * EB_PAD + b] = lh[i];  // bucket-major
        return;
    }
    typedef short wt_t[128][136];
    wt_t* wt = (wt_t*)smem;                     // [hi/lo][n][k], +8 bf16 pad
    {   // ---- stage W transposed + split (once) ----
        int k  = tid >> 1;
        int cq = tid & 1;
        const float* Wsrc = cq ? Wr : Wl;
#pragma unroll
        for (int u = 0; u < 16; ++u) {
            int c0 = u * 4;
            float4 wv = *(const float4*)(Wsrc + (size_t)k * 64 + c0);
            float vv[4] = {wv.x, wv.y, wv.z, wv.w};
#pragma unroll
            for (int q = 0; q < 4; ++q) {
                int c = cq * 64 + c0 + q;
                short hi = f2bf(vv[q]);
                wt[0][c][k] = hi;
                wt[1][c][k] = f2bf(vv[q] - bf2f(hi));
            }
        }
    }
    __syncthreads();
    int lane = tid & 63, w = tid >> 6;
    int m = lane & 31, half = lane >> 5;
    int row = blockIdx.x * 128 + w * 32 + m;
    bool rv = row < N_NODES;
    const float* xrow = x + (size_t)(rv ? row : 0) * F_IN;
    f32x16 acc[4];
#pragma unroll
    for (int t = 0; t < 4; ++t)
#pragma unroll
        for (int i = 0; i < 16; ++i) acc[t][i] = 0.f;

#pragma unroll
    for (int kt = 0; kt < 8; ++kt) {            // K=16 steps
        int kb = kt * 16 + half * 8;
        float4 xa = rv ? *(const float4*)(xrow + kb)
                       : make_float4(0.f, 0.f, 0.f, 0.f);
        float4 xb = rv ? *(const float4*)(xrow + kb + 4)
                       : make_float4(0.f, 0.f, 0.f, 0.f);
        float xs[8] = {xa.x, xa.y, xa.z, xa.w, xb.x, xb.y, xb.z, xb.w};
        bf16x8 ahi, alo;
#pragma unroll
        for (int j = 0; j < 8; ++j) {
            short hi = f2bf(xs[j]);
            ahi[j] = hi;
            alo[j] = f2bf(xs[j] - bf2f(hi));
        }
#pragma unroll
        for (int t = 0; t < 4; ++t) {
            int n = t * 32 + m;
            bf16x8 bhi = *(const bf16x8*)&wt[0][n][kb];
            bf16x8 blo = *(const bf16x8*)&wt[1][n][kb];
            acc[t] = __builtin_amdgcn_mfma_f32_32x32x16_bf16(ahi, bhi, acc[t], 0, 0, 0);
            acc[t] = __builtin_amdgcn_mfma_f32_32x32x16_bf16(ahi, blo, acc[t], 0, 0, 0);
            acc[t] = __builtin_amdgcn_mfma_f32_32x32x16_bf16(alo, bhi, acc[t], 0, 0, 0);
        }
    }
    int r0 = blockIdx.x * 128 + w * 32 + 4 * half;
#pragma unroll
    for (int t = 0; t < 4; ++t)
#pragma unroll
        for (int reg = 0; reg < 16; ++reg) {
            int rr = r0 + (reg & 3) + 8 * (reg >> 2);
            if (rr < N_NODES) {
                if (t < 2)  // xl cols 0-63 -> bf16
                    xlb[(size_t)rr * 64 + t * 32 + m] = f2bf(acc[t][reg]);
                else        // xr cols 64-127 -> f32
                    xr[(size_t)rr * 64 + (t - 2) * 32 + m] = acc[t][reg];
            }
        }
}

// ========== K2: wave-per-bucket exclusive scan over blocks + bounds ===========
__global__ __launch_bounds__(256) void k_colprefix_bounds(int* __restrict__ bhist,
                                                          int* __restrict__ colsum,
                                                          const int* __restrict__ batch,
                                                          int* __restrict__ start) {
    if (blockIdx.x < CPW_BLOCKS) {
        int wv = blockIdx.x * 4 + (threadIdx.x >> 6);   // bucket id, wave-uniform
        if (wv >= NB) return;
        int lane = threadIdx.x & 63;
        int* row = bhist + (size_t)wv * EB_PAD;
        int carry = 0;
        for (int base = 0; base < EB; base += 64) {
            int idx = base + lane;
            int v = (idx < EB) ? row[idx] : 0;
            int inc = v;
#pragma unroll
            for (int o = 1; o < 64; o <<= 1) {
                int t = __shfl_up(inc, o, 64);
                if (lane >= o) inc += t;
            }
            int tot = __shfl(inc, 63, 64);
            if (idx < EB) row[idx] = carry + inc - v;   // exclusive prefix
            carry += tot;
        }
        if (lane == 0) colsum[wv] = carry;
    } else {
        int i = (blockIdx.x - CPW_BLOCKS) * 256 + threadIdx.x;
        if (i >= N_NODES) return;
        int bi = batch[i];
        int bp = (i == 0) ? -1 : batch[i - 1];
        for (int g = bp + 1; g <= bi; ++g) start[g] = i;
        if (i == N_NODES - 1)
            for (int g = bi + 1; g <= N_GRAPHS; ++g) start[g] = N_NODES;
    }
}

// ========== K3: scatter edges into coarse buckets; redundant colbase scan =====
__global__ __launch_bounds__(256) void k_bscatter(const int* __restrict__ ei,
                                                  const int* __restrict__ bhist,
                                                  const int* __restrict__ colsum,
                                                  int* __restrict__ colbase,
                                                  int* __restrict__ bpack) {
    __shared__ int lh[NB];
    __shared__ int cb[NB + 1];
    __shared__ int sctmp[256];
    int tid = threadIdx.x, b = blockIdx.x;
    {   // redundant exclusive scan of colsum -> cb (per block, wall-hidden)
        int v[7]; int s = 0;
#pragma unroll
        for (int k = 0; k < 7; ++k) {
            int idx = tid * 7 + k;
            v[k] = (idx < NB) ? colsum[idx] : 0;
            s += v[k];
        }
        sctmp[tid] = s; __syncthreads();
        for (int off = 1; off < 256; off <<= 1) {
            int xv = (tid >= off) ? sctmp[tid - off] : 0;
            __syncthreads();
            sctmp[tid] += xv;
            __syncthreads();
        }
        int run = sctmp[tid] - s;
#pragma unroll
        for (int k = 0; k < 7; ++k) {
            int idx = tid * 7 + k;
            if (idx <= NB) cb[idx] = run;
            run += v[k];
        }
    }
    for (int i = tid; i < NB; i += 256) lh[i] = 0;
    __syncthreads();
    if (b == 0)                                 // publish colbase for k_fine
        for (int i = tid; i <= NB; i += 256) colbase[i] = cb[i];
    int e0 = b * 4096;
#pragma unroll
    for (int j = 0; j < 16; ++j) {
        int e = e0 + j * 256 + tid;
        if (e < E_TOT) {
            int s, d;
            if (e < N_EDGES) { s = ei[e]; d = ei[N_EDGES + e]; }
            else             { s = d = e - N_EDGES; }
            int bk = d >> 6;
            int lr = atomicAdd(&lh[bk], 1);
            int pos = cb[bk] + bhist[(size_t)bk * EB_PAD + b] + lr;
            bpack[pos] = s | ((d & 63) << 17);  // src in 17 bits, local dst in 6
        }
    }
}

// ========== K4: per-bucket fine grouping -> rowptr + sorted_src ===============
__global__ __launch_bounds__(256) void k_fine(const int* __restrict__ bpack,
                                              const int* __restrict__ colbase,
                                              int* __restrict__ rowptr,
                                              int* __restrict__ sorted_src) {
    __shared__ int fcnt[64];
    __shared__ int foff[64];
    int i = blockIdx.x, tid = threadIdx.x;
    int cb0 = colbase[i], cb1 = colbase[i + 1];
    if (tid < 64) fcnt[tid] = 0;
    __syncthreads();
    for (int e = cb0 + tid; e < cb1; e += 256)
        atomicAdd(&fcnt[bpack[e] >> 17], 1);
    __syncthreads();
    if (tid < 64) {                             // wave 0: scan of 64 counts
        int v = fcnt[tid];
        int inc = v;
#pragma unroll
        for (int o = 1; o < 64; o <<= 1) {
            int t = __shfl_up(inc, o, 64);
            if (tid >= o) inc += t;
        }
        int excl = inc - v;
        foff[tid] = excl;
        int node = i * 64 + tid;
        if (node <= N_NODES) rowptr[node] = cb0 + excl;
    }
    __syncthreads();
    for (int e = cb0 + tid; e < cb1; e += 256) {
        int w = bpack[e];
        int lr = atomicAdd(&foff[w >> 17], 1);
        sorted_src[cb0 + lr] = w & 131071;
    }
}

// ========== K5: GATv2 per dst — bf16 gathers, 8 lanes/edge, quad-DPP logits ===
// lane = grp*8+sub: grp = edge slot (0..7), sub = channel octet (channels sub*8..+7).
// Head of a lane = sub>>2 (quads align with heads).
__global__ __launch_bounds__(256) void k_gat(const short* __restrict__ xlb,
                                             const float* __restrict__ xr,
                                             const int* __restrict__ rowptr,
                                             const int* __restrict__ sorted_src,
                                             const float* __restrict__ att,
                                             const float* __restrict__ bias,
                                             const float* __restrict__ w_rel,
                                             const float* __restrict__ w_root,
                                             float* __restrict__ hfeat,
                                             float* __restrict__ tbuf,
                                             float* __restrict__ rbuf) {
    int lane = threadIdx.x & 63;
    int du = __builtin_amdgcn_readfirstlane(blockIdx.x * 4 + (threadIdx.x >> 6));
    if (du >= N_NODES) return;
    int grp = lane >> 3, sub = lane & 7;
    float xr8[8], att8[8];
    {
        float4 a = *(const float4*)(xr + (size_t)du * 64 + sub * 8);
        float4 b = *(const float4*)(xr + (size_t)du * 64 + sub * 8 + 4);
        xr8[0]=a.x; xr8[1]=a.y; xr8[2]=a.z; xr8[3]=a.w;
        xr8[4]=b.x; xr8[5]=b.y; xr8[6]=b.z; xr8[7]=b.w;
        float4 c = *(const float4*)(att + sub * 8);
        float4 d = *(const float4*)(att + sub * 8 + 4);
        att8[0]=c.x; att8[1]=c.y; att8[2]=c.z; att8[3]=c.w;
        att8[4]=d.x; att8[5]=d.y; att8[6]=d.z; att8[7]=d.w;
    }
    int j0 = __builtin_amdgcn_readfirstlane(rowptr[du]);
    int j1 = __builtin_amdgcn_readfirstlane(rowptr[du + 1]);   // >= j0+1
    float wsum = 0.f;
    float acc8[8] = {0.f,0.f,0.f,0.f,0.f,0.f,0.f,0.f};
    for (int jc = j0; jc < j1; jc += 8) {
        int n = j1 - jc;                        // wave-uniform
        int jj = jc + grp;
        if (jj > j1 - 1) jj = j1 - 1;
        int s = sorted_src[jj];
        bf16x8 xb = *(const bf16x8*)(xlb + (size_t)(unsigned)s * 64 + sub * 8);
        float xv8[8];
#pragma unroll
        for (int j = 0; j < 8; ++j) xv8[j] = bf2f(xb[j]);
        float p = 0.f;
#pragma unroll
        for (int j = 0; j < 8; ++j) {
            float v = xv8[j] + xr8[j];
            v = fmaxf(v, NEG_SLOPE * v);        // leaky-relu
            p += v * att8[j];
        }
        p = quad_sum(p);                        // per-head logit (quad == head)
        float w = __expf(p);                    // logits bounded; no max needed
        if (grp >= n) w = 0.f;                  // mask tail slots
        wsum += w;
#pragma unroll
        for (int j = 0; j < 8; ++j) acc8[j] += w * xv8[j];
    }
    // ---- combine the 8 edge-groups (lanes sub, sub+8, ..., sub+56) ----
    wsum += __shfl_xor(wsum, 8, 64);
    wsum += __shfl_xor(wsum, 16, 64);
    wsum += __shfl_xor(wsum, 32, 64);
#pragma unroll
    for (int j = 0; j < 8; ++j) {
        acc8[j] += __shfl_xor(acc8[j], 8, 64);
        acc8[j] += __shfl_xor(acc8[j], 16, 64);
        acc8[j] += __shfl_xor(acc8[j], 32, 64);
    }
    float h8[8];
#pragma unroll
    for (int j = 0; j < 8; ++j)
        h8[j] = acc8[j] / wsum + bias[sub * 8 + j];
    if (grp == 0) {                             // lanes 0-7 store 64 channels
        float4 s0 = make_float4(h8[0], h8[1], h8[2], h8[3]);
        float4 s1 = make_float4(h8[4], h8[5], h8[6], h8[7]);
        *(float4*)(hfeat + (size_t)du * 64 + sub * 8)     = s0;
        *(float4*)(hfeat + (size_t)du * 64 + sub * 8 + 4) = s1;
    }
    float a = 0.f, b = 0.f;
#pragma unroll
    for (int j = 0; j < 8; ++j) {
        a += h8[j] * w_rel[sub * 8 + j];
        b += h8[j] * w_root[sub * 8 + j];
    }
    a = full_sum64(a) * 0.125f;                 // 8 replicas -> /8
    b = full_sum64(b) * 0.125f;
    if (lane == 63) { tbuf[du] = a; rbuf[du] = b; }
}

// ========== K6: fused score + per-graph softmax-pool (block per graph) ========
__global__ __launch_bounds__(256) void k_pool(const int* __restrict__ rowptr,
                                              const int* __restrict__ sorted_src,
                                              const float* __restrict__ t,
                                              const float* __restrict__ r,
                                              const float* __restrict__ b_score,
                                              float* __restrict__ score,
                                              const float* __restrict__ h,
                                              const int* __restrict__ start,
                                              float* __restrict__ out) {
    __shared__ float sh[4];
    __shared__ float shacc[4][64];
    int g = blockIdx.x;
    int tid = threadIdx.x, w = tid >> 6, lane = tid & 63;
    int n0 = start[g], n1 = start[g + 1];
    int cnt = n1 - n0;
    if (cnt <= 0) { if (tid < 64) out[(size_t)g * 64 + tid] = 0.f; return; }
    float bsc = b_score[0];
    // --- phase 1: scores via sorted CSR, 4 threads per node + quad reduce
    for (int base = n0; base < n1; base += 64) {
        int i = base + (tid >> 2);
        float sum = 0.f;
        int jj0 = 0, jj1 = 0;
        if (i < n1) { jj0 = rowptr[i]; jj1 = rowptr[i + 1]; }
        for (int j = jj0 + (tid & 3); j < jj1; j += 4)
            sum += t[sorted_src[j]];
        sum = quad_sum(sum);
        if (i < n1 && (tid & 3) == 0)
            score[i] = sum - t[i] + r[i] + bsc;
    }
    __syncthreads();
    // --- phase 2a: max, then overwrite score with exp(score-m); sum exps
    float m = -1e30f;
    for (int i = n0 + tid; i < n1; i += 256) m = fmaxf(m, score[i]);
#pragma unroll
    for (int o = 32; o; o >>= 1) m = fmaxf(m, __shfl_xor(m, o, 64));
    if (lane == 0) sh[w] = m;
    __syncthreads();
    m = fmaxf(fmaxf(sh[0], sh[1]), fmaxf(sh[2], sh[3]));
    __syncthreads();
    float ssum = 0.f;
    for (int i = n0 + tid; i < n1; i += 256) {
        float e = __expf(score[i] - m);
        score[i] = e;
        ssum += e;
    }
#pragma unroll
    for (int o = 32; o; o >>= 1) ssum += __shfl_xor(ssum, o, 64);
    if (lane == 0) sh[w] = ssum;
    __syncthreads();
    ssum = sh[0] + sh[1] + sh[2] + sh[3];
    // --- phase 2b: weighted feature accumulation (no redundant exps)
    float acc = 0.f;
    for (int i = n0 + w; i < n1; i += 4)
        acc += score[i] * h[(size_t)i * 64 + lane];
    shacc[w][lane] = acc;
    __syncthreads();
    if (w == 0) {
        float tot = shacc[0][lane] + shacc[1][lane] + shacc[2][lane] + shacc[3][lane];
        out[(size_t)g * 64 + lane] = tot * (1.f + 1.f / (float)cnt) / ssum;
    }
}

extern "C" void kernel_launch(void* const* d_in, const int* in_sizes, int n_in,
                              void* d_out, int out_size, void* d_ws, size_t ws_size,
                              hipStream_t stream) {
    const float* x      = (const float*)d_in[0];
    const int*   ei     = (const int*)d_in[1];
    const int*   batch  = (const int*)d_in[2];
    const float* Wl     = (const float*)d_in[3];
    const float* Wr     = (const float*)d_in[4];
    const float* att    = (const float*)d_in[5];
    const float* bias   = (const float*)d_in[6];
    const float* w_rel  = (const float*)d_in[7];
    const float* w_root = (const float*)d_in[8];
    const float* b_sc   = (const float*)d_in[9];

    char* ws = (char*)d_ws;
    size_t off = 0;
    auto alloc = [&](size_t bytes) { void* p = ws + off; off += (bytes + 255) & ~255ull; return p; };
    float* xr         = (float*)alloc((size_t)N_NODES * 64 * 4);        // 25.6 MB
    short* xlb        = (short*)alloc((size_t)N_NODES * 64 * 2);        // 12.8 MB
    float* hfeat      = (float*)alloc((size_t)N_NODES * 64 * 4);        // 25.6 MB
    int*   bhist      = (int*)hfeat;   // alias: bhist dead before k_gat writes hfeat
    int*   bpack      = (int*)  alloc((size_t)E_TOT * 4);               // 4.4 MB
    int*   sorted_src = (int*)  alloc((size_t)E_TOT * 4);               // 4.4 MB
    int*   rowptr     = (int*)  alloc((size_t)(N_NODES + 1) * 4);
    int*   colsum     = (int*)  alloc((size_t)NB * 4);
    int*   colbase    = (int*)  alloc((size_t)(NB + 1) * 4);
    float* tbuf       = (float*)alloc((size_t)N_NODES * 4);
    float* rbuf       = (float*)alloc((size_t)N_NODES * 4);
    float* score      = (float*)alloc((size_t)N_NODES * 4);
    int*   start      = (int*)  alloc((size_t)(N_GRAPHS + 1) * 4);

    k_gemm_bhist      <<<GEMM_BLOCKS + EB, 256, 0, stream>>>(x, Wl, Wr, ei, xr, xlb, bhist);
    k_colprefix_bounds<<<CPW_BLOCKS + NODE_BLOCKS, 256, 0, stream>>>(bhist, colsum, batch, start);
    k_bscatter        <<<EB, 256, 0, stream>>>(ei, bhist, colsum, colbase, bpack);
    k_fine            <<<NB, 256, 0, stream>>>(bpack, colbase, rowptr, sorted_src);
    k_gat             <<<(N_NODES + 3) / 4, 256, 0, stream>>>(xlb, xr, rowptr, sorted_src, att, bias,
                                                              w_rel, w_root, hfeat, tbuf, rbuf);
    k_pool            <<<N_GRAPHS, 256, 0, stream>>>(rowptr, sorted_src, tbuf, rbuf, b_sc,
                                                     score, hfeat, start, (float*)d_out);
}